// Round 2
// baseline (397.484 us; speedup 1.0000x reference)
//
#include <hip/hip_runtime.h>
#include <hip/hip_bf16.h>

#define HH 56
#define WWD 56
#define CC 384
#define HWW (HH*WWD)         // 3136
#define MM (16*HWW)          // 50176

typedef __attribute__((ext_vector_type(8))) short bf16x8;
typedef __attribute__((ext_vector_type(4))) int   int4v;
typedef __attribute__((ext_vector_type(4))) float f32x4;

__device__ __forceinline__ unsigned short f2bf(float f) {
    union { float f; unsigned u; } v; v.f = f;
    unsigned r = v.u + 0x7fffu + ((v.u >> 16) & 1u);
    return (unsigned short)(r >> 16);
}
__device__ __forceinline__ bf16x8 asbf(int4v v) {
    union { int4v i; bf16x8 b; } u; u.i = v; return u.b;
}

// K-permutation: group channels by shift d. Order: [d=+2 (48) | +1 (96) | 0 (96) | -1 (96) | -2 (48)]
// d[c%8] = {2,1,0,-1,-2,-1,0,1}
__device__ __forceinline__ int invp(int k) {
    if (k < 48)  return 8*k;
    if (k < 144) { int j = k-48;  return 8*(j>>1) + ((j&1) ? 7 : 1); }
    if (k < 240) { int j = k-144; return 8*(j>>1) + ((j&1) ? 6 : 2); }
    if (k < 336) { int j = k-240; return 8*(j>>1) + ((j&1) ? 5 : 3); }
    return 8*(k-336) + 4;
}
__device__ __forceinline__ int dcls(int k) {
    return k < 48 ? 2 : k < 144 ? 1 : k < 240 ? 0 : k < 336 ? -1 : -2;
}

// x (B,H,W,C) fp32 -> xt (B,W,H,Cperm) bf16, plus per-(b,h,k') row sums R
__global__ __launch_bounds__(384)
void prep_x(const float* __restrict__ x, unsigned short* __restrict__ xt,
            float* __restrict__ R)
{
    int bid = blockIdx.x;            // b*56 + h
    int b = bid / HH, h = bid - b*HH;
    int t = threadIdx.x;             // k'
    int c = invp(t);
    const float* xp = x + ((size_t)bid*WWD)*CC + c;          // x[b][h][w=0][c]
    unsigned short* xo = xt + ((size_t)b*HWW + h)*CC + t;    // xt[b][w=0][h][k']
    float rs = 0.f;
    for (int w = 0; w < WWD; ++w) {
        float v = xp[(size_t)w*CC];
        rs += v;
        xo[(size_t)w*HH*CC] = f2bf(v);
    }
    R[(size_t)bid*CC + t] = rs;
}

// weights fp32 (k,n) -> bf16 transposed (n,k'), rows permuted for w_h/w_c
__global__ __launch_bounds__(256)
void prep_w(const float* __restrict__ w_h, const float* __restrict__ w_c,
            const float* __restrict__ w_p,
            unsigned short* __restrict__ wTh, unsigned short* __restrict__ wTc,
            unsigned short* __restrict__ wTp)
{
    __shared__ float tile[32][33];
    int mat = blockIdx.z;
    const float* src = mat == 0 ? w_h : (mat == 1 ? w_c : w_p);
    unsigned short* dst = mat == 0 ? wTh : (mat == 1 ? wTc : wTp);
    int ky = blockIdx.y*32, nx = blockIdx.x*32;
    int tx = threadIdx.x & 31, ty = threadIdx.x >> 5;
    #pragma unroll
    for (int r = ty; r < 32; r += 8) {
        int c = (mat < 2) ? invp(ky + r) : (ky + r);
        tile[r][tx] = src[(size_t)c*CC + nx + tx];
    }
    __syncthreads();
    #pragma unroll
    for (int r = ty; r < 32; r += 8)
        dst[(size_t)(nx + r)*CC + ky + tx] = f2bf(tile[tx][r]);
}

// per-batch: colsums -> exact means (shifted via border correction) -> a -> GELU MLP -> softmax -> lam
__global__ __launch_bounds__(384)
void mlp_k(const float* __restrict__ R,
           const float* __restrict__ w_h, const float* __restrict__ b_h,
           const float* __restrict__ w_c, const float* __restrict__ b_c,
           const float* __restrict__ w_r1, const float* __restrict__ b_r1,
           const float* __restrict__ w_r2, const float* __restrict__ b_r2,
           float2* __restrict__ lam)
{
    __shared__ float mh[CC], mc[CC], aa[CC], r1p[4][96];
    int b = blockIdx.x, t = threadIdx.x;
    const float* Rb = R + (size_t)b*HH*CC;
    float S = 0.f;
    for (int h = 0; h < HH; ++h) S += Rb[(size_t)h*CC + t];
    int d = dcls(t);
    float adj = 0.f;
    if (d == 2)       adj = Rb[0*CC + t] + Rb[1*CC + t];
    else if (d == 1)  adj = Rb[0*CC + t];
    else if (d == -1) adj = Rb[55*CC + t];
    else if (d == -2) adj = Rb[54*CC + t] + Rb[55*CC + t];
    const float inv = 1.f / (float)HWW;
    mh[t] = (S - adj) * inv;
    mc[t] = S * inv;
    __syncthreads();
    float sh = 0.f, sc = 0.f;
    for (int k = 0; k < CC; ++k) {
        int c = invp(k);
        sh += mh[k] * w_h[(size_t)c*CC + t];
        sc += mc[k] * w_c[(size_t)c*CC + t];
    }
    aa[t] = 2.f*(sh + b_h[t]) + (sc + b_c[t]);
    __syncthreads();
    {
        int j = t % 96, p = t / 96;
        float s = 0.f;
        for (int k = p*96; k < p*96 + 96; ++k) s += aa[k] * w_r1[(size_t)k*96 + j];
        r1p[p][j] = s;
    }
    __syncthreads();
    if (t < 96) {
        float s = r1p[0][t] + r1p[1][t] + r1p[2][t] + r1p[3][t] + b_r1[t];
        r1p[0][t] = 0.5f*s*(1.f + erff(s*0.70710678118654752f));
    }
    __syncthreads();
    float s0 = b_r2[3*t], s1 = b_r2[3*t+1], s2 = b_r2[3*t+2];
    for (int q = 0; q < 96; ++q) {
        float rv = r1p[0][q];
        const float* wp = w_r2 + (size_t)q*(3*CC) + 3*t;
        s0 += rv*wp[0]; s1 += rv*wp[1]; s2 += rv*wp[2];
    }
    float mx = fmaxf(s0, fmaxf(s1, s2));
    float e0 = expf(s0-mx), e1 = expf(s1-mx), e2 = expf(s2-mx);
    float dn = 1.f/(e0+e1+e2);
    lam[(size_t)b*CC + t] = make_float2((e0+e1)*dn, e2*dn);
}

// G1: dual GEMM (shifted-A@w_h, A@w_c) from one LDS panel, combine with lam -> A' bf16
__global__ __launch_bounds__(256, 2)
void g1_k(const unsigned short* __restrict__ xt,
          const unsigned short* __restrict__ wTh,
          const unsigned short* __restrict__ wTc,
          const float* __restrict__ b_h, const float* __restrict__ b_c,
          const float2* __restrict__ lam,
          unsigned short* __restrict__ Ap)
{
    __shared__ unsigned short As[68*CC];   // 52,224 B, XOR-swizzled octets
    const int tid = threadIdx.x;
    const int m0 = blockIdx.x * 64;
    #pragma unroll
    for (int it = 0; it < 13; ++it) {
        int s = it*256 + tid;
        if (s < 68*48) {
            int row = s / 48, oct = s - row*48;
            int g = m0 - 2 + row;
            g = g < 0 ? 0 : (g >= MM ? MM-1 : g);
            int4v v = *(const int4v*)(xt + (size_t)g*CC + oct*8);
            *(int4v*)&As[row*CC + ((oct ^ (row & 7)) << 3)] = v;
        }
    }
    __syncthreads();

    const int lane = tid & 63;
    const int wid  = tid >> 6;
    const int l16  = lane & 15;
    const int lhi  = lane >> 4;
    const int wm = (wid >> 1) * 32;
    const int wn = (wid & 1) * 64;
    const int b  = m0 / HWW;

    int mrow[2], hmod[2];
    #pragma unroll
    for (int mi = 0; mi < 2; ++mi) {
        mrow[mi] = wm + mi*16 + l16 + 2;
        hmod[mi] = (m0 + wm + mi*16 + l16) % HH;
    }

    #pragma unroll 1
    for (int nt = 0; nt < 3; ++nt) {
        const int n0 = nt*128 + wn;
        f32x4 ah[2][4], ac[2][4];
        #pragma unroll
        for (int mi = 0; mi < 2; ++mi)
            #pragma unroll
            for (int ni = 0; ni < 4; ++ni) { ah[mi][ni] = (f32x4)0.f; ac[mi][ni] = (f32x4)0.f; }

        #pragma unroll 3
        for (int kt = 0; kt < 12; ++kt) {
            const int oct = kt*4 + lhi;
            const int d = oct < 6 ? 2 : oct < 18 ? 1 : oct < 30 ? 0 : oct < 42 ? -1 : -2;
            int4v ap[2], ash[2];
            #pragma unroll
            for (int mi = 0; mi < 2; ++mi) {
                int rp = mrow[mi];
                ap[mi] = *(const int4v*)&As[rp*CC + ((oct ^ (rp & 7)) << 3)];
                int rs = rp + d;
                int4v v = *(const int4v*)&As[rs*CC + ((oct ^ (rs & 7)) << 3)];
                int ok = ((unsigned)(hmod[mi] + d) < (unsigned)HH) ? ~0 : 0;
                v &= ok;
                ash[mi] = v;
            }
            int4v bh[4], bc[4];
            #pragma unroll
            for (int ni = 0; ni < 4; ++ni) {
                size_t boff = (size_t)(n0 + ni*16 + l16)*CC + kt*32 + lhi*8;
                bh[ni] = *(const int4v*)(wTh + boff);
                bc[ni] = *(const int4v*)(wTc + boff);
            }
            #pragma unroll
            for (int mi = 0; mi < 2; ++mi)
                #pragma unroll
                for (int ni = 0; ni < 4; ++ni) {
                    ah[mi][ni] = __builtin_amdgcn_mfma_f32_16x16x32_bf16(
                        asbf(ash[mi]), asbf(bh[ni]), ah[mi][ni], 0, 0, 0);
                    ac[mi][ni] = __builtin_amdgcn_mfma_f32_16x16x32_bf16(
                        asbf(ap[mi]), asbf(bc[ni]), ac[mi][ni], 0, 0, 0);
                }
        }
        #pragma unroll
        for (int ni = 0; ni < 4; ++ni) {
            int n = n0 + ni*16 + l16;
            float2 L = lam[(size_t)b*CC + n];
            float bh_ = b_h[n], bc_ = b_c[n];
            #pragma unroll
            for (int mi = 0; mi < 2; ++mi) {
                int r = m0 + wm + mi*16 + lhi*4;
                #pragma unroll
                for (int j = 0; j < 4; ++j) {
                    float v = L.x*(ah[mi][ni][j] + bh_) + L.y*(ac[mi][ni][j] + bc_);
                    Ap[(size_t)(r + j)*CC + n] = f2bf(v);
                }
            }
        }
    }
}

// G2: A' @ w_p + b_p -> out fp32, rows permuted back to (b,h,w)
__global__ __launch_bounds__(256, 2)
void g2_k(const unsigned short* __restrict__ Ap,
          const unsigned short* __restrict__ wTp,
          const float* __restrict__ b_p,
          float* __restrict__ out)
{
    __shared__ unsigned short As[64*CC];   // 49,152 B
    const int tid = threadIdx.x;
    const int m0 = blockIdx.x * 64;
    #pragma unroll
    for (int it = 0; it < 12; ++it) {
        int s = it*256 + tid;
        int row = s / 48, oct = s - row*48;
        int4v v = *(const int4v*)(Ap + (size_t)(m0 + row)*CC + oct*8);
        *(int4v*)&As[row*CC + ((oct ^ (row & 7)) << 3)] = v;
    }
    __syncthreads();

    const int lane = tid & 63;
    const int wid  = tid >> 6;
    const int l16  = lane & 15;
    const int lhi  = lane >> 4;
    const int wm = (wid >> 1) * 32;
    const int wn = (wid & 1) * 64;

    int ro[2][4];
    #pragma unroll
    for (int mi = 0; mi < 2; ++mi)
        #pragma unroll
        for (int j = 0; j < 4; ++j) {
            int r = m0 + wm + mi*16 + lhi*4 + j;
            int tt = r % HWW;
            int hh = tt % HH, ww = tt / HH;
            ro[mi][j] = (r - tt) + hh*WWD + ww;
        }

    #pragma unroll 1
    for (int nt = 0; nt < 3; ++nt) {
        const int n0 = nt*128 + wn;
        f32x4 acc[2][4];
        #pragma unroll
        for (int mi = 0; mi < 2; ++mi)
            #pragma unroll
            for (int ni = 0; ni < 4; ++ni) acc[mi][ni] = (f32x4)0.f;

        #pragma unroll 4
        for (int kt = 0; kt < 12; ++kt) {
            const int oct = kt*4 + lhi;
            int4v a[2], bb[4];
            #pragma unroll
            for (int mi = 0; mi < 2; ++mi) {
                int rp = wm + mi*16 + l16;
                a[mi] = *(const int4v*)&As[rp*CC + ((oct ^ (rp & 7)) << 3)];
            }
            #pragma unroll
            for (int ni = 0; ni < 4; ++ni)
                bb[ni] = *(const int4v*)(wTp + (size_t)(n0 + ni*16 + l16)*CC + kt*32 + lhi*8);
            #pragma unroll
            for (int mi = 0; mi < 2; ++mi)
                #pragma unroll
                for (int ni = 0; ni < 4; ++ni)
                    acc[mi][ni] = __builtin_amdgcn_mfma_f32_16x16x32_bf16(
                        asbf(a[mi]), asbf(bb[ni]), acc[mi][ni], 0, 0, 0);
        }
        #pragma unroll
        for (int ni = 0; ni < 4; ++ni) {
            int n = n0 + ni*16 + l16;
            float bp = b_p[n];
            #pragma unroll
            for (int mi = 0; mi < 2; ++mi)
                #pragma unroll
                for (int j = 0; j < 4; ++j)
                    out[(size_t)ro[mi][j]*CC + n] = acc[mi][ni][j] + bp;
        }
    }
}

extern "C" void kernel_launch(void* const* d_in, const int* in_sizes, int n_in,
                              void* d_out, int out_size, void* d_ws, size_t ws_size,
                              hipStream_t stream)
{
    const float* x    = (const float*)d_in[0];
    const float* w_h  = (const float*)d_in[1];
    const float* b_h  = (const float*)d_in[2];
    const float* w_c  = (const float*)d_in[3];
    const float* b_c  = (const float*)d_in[4];
    const float* w_r1 = (const float*)d_in[5];
    const float* b_r1 = (const float*)d_in[6];
    const float* w_r2 = (const float*)d_in[7];
    const float* b_r2 = (const float*)d_in[8];
    const float* w_p  = (const float*)d_in[9];
    const float* b_p  = (const float*)d_in[10];
    float* out = (float*)d_out;

    char* ws = (char*)d_ws;
    const size_t XB = (size_t)MM * CC * 2;          // 38,535,168
    unsigned short* xt  = (unsigned short*)ws;
    unsigned short* Ap  = (unsigned short*)(ws + XB);
    unsigned short* wTh = (unsigned short*)(ws + 2*XB);
    unsigned short* wTc = wTh + CC*CC;
    unsigned short* wTp = wTc + CC*CC;
    float2* lam         = (float2*)(ws + 2*XB + 3*(size_t)CC*CC*2);
    float* R            = (float*)Ap;   // alias: R consumed by mlp_k BEFORE g1_k writes Ap

    prep_x<<<16*HH, 384, 0, stream>>>(x, xt, R);
    prep_w<<<dim3(12, 12, 3), 256, 0, stream>>>(w_h, w_c, w_p, wTh, wTc, wTp);
    mlp_k<<<16, 384, 0, stream>>>(R, w_h, b_h, w_c, b_c, w_r1, b_r1, w_r2, b_r2, lam);
    g1_k<<<MM/64, 256, 0, stream>>>(xt, wTh, wTc, b_h, b_c, lam, Ap);
    g2_k<<<MM/64, 256, 0, stream>>>(Ap, wTp, b_p, out);
}

// Round 3
// 340.054 us; speedup vs baseline: 1.1689x; 1.1689x over previous
//
#include <hip/hip_runtime.h>
#include <hip/hip_bf16.h>

#define HH 56
#define WWD 56
#define CC 384
#define HWW (HH*WWD)         // 3136
#define MM (16*HWW)          // 50176
#define NBLK (MM/64)         // 784

typedef __attribute__((ext_vector_type(8))) short bf16x8;
typedef __attribute__((ext_vector_type(4))) int   int4v;
typedef __attribute__((ext_vector_type(4))) float f32x4;

__device__ __forceinline__ unsigned short f2bf(float f) {
    union { float f; unsigned u; } v; v.f = f;
    unsigned r = v.u + 0x7fffu + ((v.u >> 16) & 1u);
    return (unsigned short)(r >> 16);
}
__device__ __forceinline__ float bf2f(unsigned short h) {
    union { unsigned u; float f; } v; v.u = ((unsigned)h) << 16;
    return v.f;
}
__device__ __forceinline__ bf16x8 asbf(int4v v) {
    union { int4v i; bf16x8 b; } u; u.i = v; return u.b;
}

// K-permutation: [d=+2 (48) | +1 (96) | 0 (96) | -1 (96) | -2 (48)], d[c%8]={2,1,0,-1,-2,-1,0,1}
__device__ __forceinline__ int invp(int k) {
    if (k < 48)  return 8*k;
    if (k < 144) { int j = k-48;  return 8*(j>>1) + ((j&1) ? 7 : 1); }
    if (k < 240) { int j = k-144; return 8*(j>>1) + ((j&1) ? 6 : 2); }
    if (k < 336) { int j = k-240; return 8*(j>>1) + ((j&1) ? 5 : 3); }
    return 8*(k-336) + 4;
}
__device__ __forceinline__ int dcls(int k) {
    return k < 48 ? 2 : k < 144 ? 1 : k < 240 ? 0 : k < 336 ? -1 : -2;
}

// x (B,H,W,C) fp32 -> xt (B,W,H,Cperm) bf16 (paired 4B stores) + row sums R[b,h,k']
__global__ __launch_bounds__(192)
void prep_x(const float* __restrict__ x, unsigned short* __restrict__ xt,
            float* __restrict__ R)
{
    int bid = blockIdx.x;            // b*56 + h
    int b = bid / HH, h = bid - b*HH;
    int t = threadIdx.x;             // k'-pair
    int c0 = invp(2*t), c1 = invp(2*t+1);
    const float* xp = x + ((size_t)bid*WWD)*CC;
    unsigned* xo = (unsigned*)(xt + ((size_t)b*HWW + h)*CC) + t;
    float s0 = 0.f, s1 = 0.f;
    #pragma unroll 4
    for (int w = 0; w < WWD; ++w) {
        float v0 = xp[(size_t)w*CC + c0];
        float v1 = xp[(size_t)w*CC + c1];
        s0 += v0; s1 += v1;
        xo[(size_t)w*(HH*CC/2)] = (unsigned)f2bf(v0) | ((unsigned)f2bf(v1) << 16);
    }
    R[(size_t)bid*CC + 2*t]     = s0;
    R[(size_t)bid*CC + 2*t + 1] = s1;
}

// weights fp32 (k,n) -> bf16 transposed (n,k'), rows k-permuted for w_h/w_c
__global__ __launch_bounds__(256)
void prep_w(const float* __restrict__ w_h, const float* __restrict__ w_c,
            const float* __restrict__ w_p,
            unsigned short* __restrict__ wTh, unsigned short* __restrict__ wTc,
            unsigned short* __restrict__ wTp)
{
    __shared__ float tile[32][33];
    int mat = blockIdx.z;
    const float* src = mat == 0 ? w_h : (mat == 1 ? w_c : w_p);
    unsigned short* dst = mat == 0 ? wTh : (mat == 1 ? wTc : wTp);
    int ky = blockIdx.y*32, nx = blockIdx.x*32;
    int tx = threadIdx.x & 31, ty = threadIdx.x >> 5;
    #pragma unroll
    for (int r = ty; r < 32; r += 8) {
        int c = (mat < 2) ? invp(ky + r) : (ky + r);
        tile[r][tx] = src[(size_t)c*CC + nx + tx];
    }
    __syncthreads();
    #pragma unroll
    for (int r = ty; r < 32; r += 8)
        dst[(size_t)(nx + r)*CC + ky + tx] = f2bf(tile[tx][r]);
}

// per-batch: exact means (border-corrected) -> a -> GELU MLP -> softmax -> lam + combined bias
__global__ __launch_bounds__(384)
void mlp_k(const float* __restrict__ R,
           const float* __restrict__ w_h, const float* __restrict__ b_h,
           const float* __restrict__ w_c, const float* __restrict__ b_c,
           const float* __restrict__ w_r1, const float* __restrict__ b_r1,
           const float* __restrict__ w_r2, const float* __restrict__ b_r2,
           float2* __restrict__ lam, float* __restrict__ biasc)
{
    __shared__ float mh[CC], mc[CC], aa[CC], r1p[4][96];
    int b = blockIdx.x, t = threadIdx.x;
    const float* Rb = R + (size_t)b*HH*CC;
    float S = 0.f;
    for (int h = 0; h < HH; ++h) S += Rb[(size_t)h*CC + t];
    int d = dcls(t);
    float adj = 0.f;
    if (d == 2)       adj = Rb[0*CC + t] + Rb[1*CC + t];
    else if (d == 1)  adj = Rb[0*CC + t];
    else if (d == -1) adj = Rb[55*CC + t];
    else if (d == -2) adj = Rb[54*CC + t] + Rb[55*CC + t];
    const float inv = 1.f / (float)HWW;
    mh[t] = (S - adj) * inv;
    mc[t] = S * inv;
    __syncthreads();
    float sh = 0.f, sc = 0.f;
    #pragma unroll 4
    for (int k = 0; k < CC; ++k) {
        int c = invp(k);
        sh += mh[k] * w_h[(size_t)c*CC + t];
        sc += mc[k] * w_c[(size_t)c*CC + t];
    }
    aa[t] = 2.f*(sh + b_h[t]) + (sc + b_c[t]);
    __syncthreads();
    {
        int j = t % 96, p = t / 96;
        float s = 0.f;
        for (int k = p*96; k < p*96 + 96; ++k) s += aa[k] * w_r1[(size_t)k*96 + j];
        r1p[p][j] = s;
    }
    __syncthreads();
    if (t < 96) {
        float s = r1p[0][t] + r1p[1][t] + r1p[2][t] + r1p[3][t] + b_r1[t];
        r1p[0][t] = 0.5f*s*(1.f + erff(s*0.70710678118654752f));
    }
    __syncthreads();
    float s0 = b_r2[3*t], s1 = b_r2[3*t+1], s2 = b_r2[3*t+2];
    for (int q = 0; q < 96; ++q) {
        float rv = r1p[0][q];
        const float* wp = w_r2 + (size_t)q*(3*CC) + 3*t;
        s0 += rv*wp[0]; s1 += rv*wp[1]; s2 += rv*wp[2];
    }
    float mx = fmaxf(s0, fmaxf(s1, s2));
    float e0 = expf(s0-mx), e1 = expf(s1-mx), e2 = expf(s2-mx);
    float dn = 1.f/(e0+e1+e2);
    float lh = (e0+e1)*dn, lc = e2*dn;
    lam[(size_t)b*CC + t] = make_float2(lh, lc);
    biasc[(size_t)b*CC + t] = lh*b_h[t] + lc*b_c[t];
}

// per-batch combined B: wB[b][n][0:384]=lh*wTh[n][:], [384:768]=lc*wTc[n][:]
__global__ __launch_bounds__(256)
void wcomb_k(const unsigned short* __restrict__ wTh,
             const unsigned short* __restrict__ wTc,
             const float2* __restrict__ lam,
             unsigned short* __restrict__ wB)
{
    int idx = blockIdx.x*256 + threadIdx.x;       // (b, n, o)
    int b = idx / (CC*96);
    int r = idx - b*(CC*96);
    int n = r / 96, o = r - n*96;
    float2 L = lam[(size_t)b*CC + n];
    bool hh = o < 48;
    const unsigned short* src = hh ? (wTh + (size_t)n*CC + o*8)
                                   : (wTc + (size_t)n*CC + (size_t)(o-48)*8);
    float s = hh ? L.x : L.y;
    bf16x8 v = *(const bf16x8*)src;
    bf16x8 ov;
    #pragma unroll
    for (int j = 0; j < 8; ++j) ov[j] = (short)f2bf(s * bf2f((unsigned short)v[j]));
    *(bf16x8*)(wB + (size_t)b*(CC*768) + (size_t)n*768 + o*8) = ov;
}

// G1: A' = [A_shift | A] @ wB[b] + biasc  (K=768, single acc, full N=384 per block)
__global__ __launch_bounds__(512, 4)
void g1_k(const unsigned short* __restrict__ xt,
          const unsigned short* __restrict__ wB,
          const float* __restrict__ biasc,
          unsigned short* __restrict__ Ap)
{
    __shared__ unsigned short As[68*CC];          // 52,224 B, XOR-swizzled octets
    const int tid = threadIdx.x;
    int bid = blockIdx.x;
    bid = (bid & 7)*(NBLK/8) + (bid >> 3);        // XCD-chunked swizzle (784=8*98)
    const int m0 = bid * 64;
    const int b  = m0 / HWW;

    #pragma unroll
    for (int it = 0; it < 7; ++it) {
        int s = it*512 + tid;
        if (s < 68*48) {
            int row = s / 48, oct = s - row*48;
            int g = m0 - 2 + row;
            g = g < 0 ? 0 : (g >= MM ? MM-1 : g);
            int4v v = *(const int4v*)(xt + (size_t)g*CC + oct*8);
            *(int4v*)&As[row*CC + ((oct ^ (row & 7)) << 3)] = v;
        }
    }
    __syncthreads();

    const int lane = tid & 63;
    const int wid  = tid >> 6;
    const int l16  = lane & 15;
    const int lhi  = lane >> 4;
    const int wm = (wid >> 2) * 32;               // 2 M-waves
    const int wn = (wid & 3) * 96;                // 4 N-waves

    int rbase[2], hmod[2];
    #pragma unroll
    for (int mi = 0; mi < 2; ++mi) {
        rbase[mi] = wm + mi*16 + l16 + 2;
        hmod[mi]  = (m0 + wm + mi*16 + l16) % HH;
    }
    const unsigned short* bp = wB + (size_t)b*(CC*768) + (size_t)(wn + l16)*768 + lhi*8;

    f32x4 acc[2][6];
    #pragma unroll
    for (int mi = 0; mi < 2; ++mi)
        #pragma unroll
        for (int ni = 0; ni < 6; ++ni) acc[mi][ni] = (f32x4)0.f;

    // K-half 1: shifted rows (k' 0..383)
    #pragma unroll 2
    for (int kt = 0; kt < 12; ++kt) {
        const int oct = kt*4 + lhi;
        const int d = oct < 6 ? 2 : oct < 18 ? 1 : oct < 30 ? 0 : oct < 42 ? -1 : -2;
        int4v a[2];
        #pragma unroll
        for (int mi = 0; mi < 2; ++mi) {
            int r = rbase[mi] + d;
            int4v v = *(const int4v*)&As[r*CC + ((oct ^ (r & 7)) << 3)];
            int ok = ((unsigned)(hmod[mi] + d) < (unsigned)HH) ? ~0 : 0;
            a[mi] = v & ok;
        }
        int4v bb[6];
        #pragma unroll
        for (int ni = 0; ni < 6; ++ni)
            bb[ni] = *(const int4v*)(bp + (size_t)ni*(16*768) + kt*32);
        #pragma unroll
        for (int mi = 0; mi < 2; ++mi)
            #pragma unroll
            for (int ni = 0; ni < 6; ++ni)
                acc[mi][ni] = __builtin_amdgcn_mfma_f32_16x16x32_bf16(
                    asbf(a[mi]), asbf(bb[ni]), acc[mi][ni], 0, 0, 0);
    }
    // K-half 2: plain rows (k' 384..767)
    #pragma unroll 2
    for (int kt = 12; kt < 24; ++kt) {
        const int oct = (kt-12)*4 + lhi;
        int4v a[2];
        #pragma unroll
        for (int mi = 0; mi < 2; ++mi) {
            int r = rbase[mi];
            a[mi] = *(const int4v*)&As[r*CC + ((oct ^ (r & 7)) << 3)];
        }
        int4v bb[6];
        #pragma unroll
        for (int ni = 0; ni < 6; ++ni)
            bb[ni] = *(const int4v*)(bp + (size_t)ni*(16*768) + kt*32);
        #pragma unroll
        for (int mi = 0; mi < 2; ++mi)
            #pragma unroll
            for (int ni = 0; ni < 6; ++ni)
                acc[mi][ni] = __builtin_amdgcn_mfma_f32_16x16x32_bf16(
                    asbf(a[mi]), asbf(bb[ni]), acc[mi][ni], 0, 0, 0);
    }

    #pragma unroll
    for (int ni = 0; ni < 6; ++ni) {
        int n = wn + ni*16 + l16;
        float bc = biasc[(size_t)b*CC + n];
        #pragma unroll
        for (int mi = 0; mi < 2; ++mi) {
            int r = m0 + wm + mi*16 + lhi*4;
            #pragma unroll
            for (int j = 0; j < 4; ++j)
                Ap[(size_t)(r + j)*CC + n] = f2bf(acc[mi][ni][j] + bc);
        }
    }
}

// G2: out = A' @ wTp + b_p, rows unpermuted to (b,h,w)
__global__ __launch_bounds__(512, 4)
void g2_k(const unsigned short* __restrict__ Ap,
          const unsigned short* __restrict__ wTp,
          const float* __restrict__ b_p,
          float* __restrict__ out)
{
    __shared__ unsigned short As[64*CC];          // 49,152 B
    const int tid = threadIdx.x;
    int bid = blockIdx.x;
    bid = (bid & 7)*(NBLK/8) + (bid >> 3);
    const int m0 = bid * 64;

    #pragma unroll
    for (int it = 0; it < 6; ++it) {
        int s = it*512 + tid;
        int row = s / 48, oct = s - row*48;
        int4v v = *(const int4v*)(Ap + (size_t)(m0 + row)*CC + oct*8);
        *(int4v*)&As[row*CC + ((oct ^ (row & 7)) << 3)] = v;
    }
    __syncthreads();

    const int lane = tid & 63;
    const int wid  = tid >> 6;
    const int l16  = lane & 15;
    const int lhi  = lane >> 4;
    const int wm = (wid >> 2) * 32;
    const int wn = (wid & 3) * 96;

    const unsigned short* bp = wTp + (size_t)(wn + l16)*CC + lhi*8;

    int ro[2][4];
    #pragma unroll
    for (int mi = 0; mi < 2; ++mi)
        #pragma unroll
        for (int j = 0; j < 4; ++j) {
            int r = m0 + wm + mi*16 + lhi*4 + j;
            int tt = r % HWW;
            int hh = tt % HH, ww = tt / HH;
            ro[mi][j] = (r - tt) + hh*WWD + ww;
        }

    f32x4 acc[2][6];
    #pragma unroll
    for (int mi = 0; mi < 2; ++mi)
        #pragma unroll
        for (int ni = 0; ni < 6; ++ni) acc[mi][ni] = (f32x4)0.f;

    #pragma unroll 2
    for (int kt = 0; kt < 12; ++kt) {
        const int oct = kt*4 + lhi;
        int4v a[2];
        #pragma unroll
        for (int mi = 0; mi < 2; ++mi) {
            int r = wm + mi*16 + l16;
            a[mi] = *(const int4v*)&As[r*CC + ((oct ^ (r & 7)) << 3)];
        }
        int4v bb[6];
        #pragma unroll
        for (int ni = 0; ni < 6; ++ni)
            bb[ni] = *(const int4v*)(bp + (size_t)ni*(16*CC) + kt*32);
        #pragma unroll
        for (int mi = 0; mi < 2; ++mi)
            #pragma unroll
            for (int ni = 0; ni < 6; ++ni)
                acc[mi][ni] = __builtin_amdgcn_mfma_f32_16x16x32_bf16(
                    asbf(a[mi]), asbf(bb[ni]), acc[mi][ni], 0, 0, 0);
    }

    #pragma unroll
    for (int ni = 0; ni < 6; ++ni) {
        int n = wn + ni*16 + l16;
        float bpv = b_p[n];
        #pragma unroll
        for (int mi = 0; mi < 2; ++mi)
            #pragma unroll
            for (int j = 0; j < 4; ++j)
                out[(size_t)ro[mi][j]*CC + n] = acc[mi][ni][j] + bpv;
    }
}

extern "C" void kernel_launch(void* const* d_in, const int* in_sizes, int n_in,
                              void* d_out, int out_size, void* d_ws, size_t ws_size,
                              hipStream_t stream)
{
    const float* x    = (const float*)d_in[0];
    const float* w_h  = (const float*)d_in[1];
    const float* b_h  = (const float*)d_in[2];
    const float* w_c  = (const float*)d_in[3];
    const float* b_c  = (const float*)d_in[4];
    const float* w_r1 = (const float*)d_in[5];
    const float* b_r1 = (const float*)d_in[6];
    const float* w_r2 = (const float*)d_in[7];
    const float* b_r2 = (const float*)d_in[8];
    const float* w_p  = (const float*)d_in[9];
    const float* b_p  = (const float*)d_in[10];
    float* out = (float*)d_out;

    char* ws = (char*)d_ws;
    const size_t XB = (size_t)MM * CC * 2;          // 38,535,168
    const size_t WT = (size_t)CC * CC * 2;          // 294,912
    unsigned short* xt  = (unsigned short*)ws;
    unsigned short* Ap  = (unsigned short*)(ws + XB);
    unsigned short* wTh = (unsigned short*)(ws + 2*XB);
    unsigned short* wTc = (unsigned short*)(ws + 2*XB + WT);
    unsigned short* wTp = (unsigned short*)(ws + 2*XB + 2*WT);
    unsigned short* wB  = (unsigned short*)(ws + 2*XB + 3*WT);          // 9,437,184
    float2* lam         = (float2*)(ws + 2*XB + 3*WT + 9437184);        // 49,152
    float*  biasc       = (float*)(ws + 2*XB + 3*WT + 9437184 + 49152); // 24,576
    float*  R           = (float*)Ap;   // alias: consumed by mlp_k before g1_k writes Ap

    prep_x<<<16*HH, 192, 0, stream>>>(x, xt, R);
    prep_w<<<dim3(12, 12, 3), 256, 0, stream>>>(w_h, w_c, w_p, wTh, wTc, wTp);
    mlp_k<<<16, 384, 0, stream>>>(R, w_h, b_h, w_c, b_c, w_r1, b_r1, w_r2, b_r2, lam, biasc);
    wcomb_k<<<(16*CC*96)/256, 256, 0, stream>>>(wTh, wTc, lam, wB);
    g1_k<<<NBLK, 512, 0, stream>>>(xt, wB, biasc, Ap);
    g2_k<<<NBLK, 512, 0, stream>>>(Ap, wTp, b_p, out);
}

// Round 4
// 215.960 us; speedup vs baseline: 1.8405x; 1.5746x over previous
//
#include <hip/hip_runtime.h>
#include <hip/hip_bf16.h>

#define HH 56
#define WWD 56
#define CC 384
#define HWW (HH*WWD)         // 3136
#define MM (16*HWW)          // 50176
#define NBLK (MM/64)         // 784

typedef __attribute__((ext_vector_type(8))) short bf16x8;
typedef __attribute__((ext_vector_type(4))) int   int4v;
typedef __attribute__((ext_vector_type(4))) float f32x4;

__device__ __forceinline__ unsigned short f2bf(float f) {
    union { float f; unsigned u; } v; v.f = f;
    unsigned r = v.u + 0x7fffu + ((v.u >> 16) & 1u);
    return (unsigned short)(r >> 16);
}
__device__ __forceinline__ float bf2f(unsigned short h) {
    union { unsigned u; float f; } v; v.u = ((unsigned)h) << 16;
    return v.f;
}
__device__ __forceinline__ bf16x8 asbf(int4v v) {
    union { int4v i; bf16x8 b; } u; u.i = v; return u.b;
}

// K-permutation: [d=+2 (48) | +1 (96) | 0 (96) | -1 (96) | -2 (48)], d[c%8]={2,1,0,-1,-2,-1,0,1}
__device__ __forceinline__ int invp(int k) {
    if (k < 48)  return 8*k;
    if (k < 144) { int j = k-48;  return 8*(j>>1) + ((j&1) ? 7 : 1); }
    if (k < 240) { int j = k-144; return 8*(j>>1) + ((j&1) ? 6 : 2); }
    if (k < 336) { int j = k-240; return 8*(j>>1) + ((j&1) ? 5 : 3); }
    return 8*(k-336) + 4;
}
__device__ __forceinline__ int dcls(int k) {
    return k < 48 ? 2 : k < 144 ? 1 : k < 240 ? 0 : k < 336 ? -1 : -2;
}

// x (B,H,W,C) fp32 -> xt (B,W,H,Cperm) bf16 + row sums R[b*56+h][k']
__global__ __launch_bounds__(192)
void prep_x(const float* __restrict__ x, unsigned short* __restrict__ xt,
            float* __restrict__ R)
{
    int bid = blockIdx.x;            // b*56 + h
    int b = bid / HH, h = bid - b*HH;
    int t = threadIdx.x;             // k'-pair
    int c0 = invp(2*t), c1 = invp(2*t+1);
    const float* xp = x + ((size_t)bid*WWD)*CC;
    unsigned* xo = (unsigned*)(xt + ((size_t)b*HWW + h)*CC) + t;
    float s0 = 0.f, s1 = 0.f;
    #pragma unroll 4
    for (int w = 0; w < WWD; ++w) {
        float v0 = xp[(size_t)w*CC + c0];
        float v1 = xp[(size_t)w*CC + c1];
        s0 += v0; s1 += v1;
        xo[(size_t)w*(HH*CC/2)] = (unsigned)f2bf(v0) | ((unsigned)f2bf(v1) << 16);
    }
    R[(size_t)bid*CC + 2*t]     = s0;
    R[(size_t)bid*CC + 2*t + 1] = s1;
}

// weights fp32 (k,n) -> bf16 transposed (n,k'), rows k-permuted for w_h/w_c
__global__ __launch_bounds__(256)
void prep_w(const float* __restrict__ w_h, const float* __restrict__ w_c,
            const float* __restrict__ w_p,
            unsigned short* __restrict__ wTh, unsigned short* __restrict__ wTc,
            unsigned short* __restrict__ wTp)
{
    __shared__ float tile[32][33];
    int mat = blockIdx.z;
    const float* src = mat == 0 ? w_h : (mat == 1 ? w_c : w_p);
    unsigned short* dst = mat == 0 ? wTh : (mat == 1 ? wTc : wTp);
    int ky = blockIdx.y*32, nx = blockIdx.x*32;
    int tx = threadIdx.x & 31, ty = threadIdx.x >> 5;
    #pragma unroll
    for (int r = ty; r < 32; r += 8) {
        int c = (mat < 2) ? invp(ky + r) : (ky + r);
        tile[r][tx] = src[(size_t)c*CC + nx + tx];
    }
    __syncthreads();
    #pragma unroll
    for (int r = ty; r < 32; r += 8)
        dst[(size_t)(nx + r)*CC + ky + tx] = f2bf(tile[tx][r]);
}

// per-batch: exact means -> a -> GELU MLP -> softmax -> lam + combined bias
__global__ __launch_bounds__(384)
void mlp_k(const float* __restrict__ R,
           const float* __restrict__ w_h, const float* __restrict__ b_h,
           const float* __restrict__ w_c, const float* __restrict__ b_c,
           const float* __restrict__ w_r1, const float* __restrict__ b_r1,
           const float* __restrict__ w_r2, const float* __restrict__ b_r2,
           float2* __restrict__ lam, float* __restrict__ biasc)
{
    __shared__ float mh[CC], mc[CC], aa[CC], r1p[4][96];
    int b = blockIdx.x, t = threadIdx.x;
    const float* Rb = R + (size_t)b*HH*CC;
    float S = 0.f;
    for (int h = 0; h < HH; ++h) S += Rb[(size_t)h*CC + t];
    int d = dcls(t);
    float adj = 0.f;
    if (d == 2)       adj = Rb[0*CC + t] + Rb[1*CC + t];
    else if (d == 1)  adj = Rb[0*CC + t];
    else if (d == -1) adj = Rb[55*CC + t];
    else if (d == -2) adj = Rb[54*CC + t] + Rb[55*CC + t];
    const float inv = 1.f / (float)HWW;
    mh[t] = (S - adj) * inv;
    mc[t] = S * inv;
    __syncthreads();
    float sh = 0.f, sc = 0.f;
    #pragma unroll 4
    for (int k = 0; k < CC; ++k) {
        int c = invp(k);
        sh += mh[k] * w_h[(size_t)c*CC + t];
        sc += mc[k] * w_c[(size_t)c*CC + t];
    }
    aa[t] = 2.f*(sh + b_h[t]) + (sc + b_c[t]);
    __syncthreads();
    {
        int j = t % 96, p = t / 96;
        float s = 0.f;
        for (int k = p*96; k < p*96 + 96; ++k) s += aa[k] * w_r1[(size_t)k*96 + j];
        r1p[p][j] = s;
    }
    __syncthreads();
    if (t < 96) {
        float s = r1p[0][t] + r1p[1][t] + r1p[2][t] + r1p[3][t] + b_r1[t];
        r1p[0][t] = 0.5f*s*(1.f + erff(s*0.70710678118654752f));
    }
    __syncthreads();
    float s0 = b_r2[3*t], s1 = b_r2[3*t+1], s2 = b_r2[3*t+2];
    for (int q = 0; q < 96; ++q) {
        float rv = r1p[0][q];
        const float* wp = w_r2 + (size_t)q*(3*CC) + 3*t;
        s0 += rv*wp[0]; s1 += rv*wp[1]; s2 += rv*wp[2];
    }
    float mx = fmaxf(s0, fmaxf(s1, s2));
    float e0 = expf(s0-mx), e1 = expf(s1-mx), e2 = expf(s2-mx);
    float dn = 1.f/(e0+e1+e2);
    float lh = (e0+e1)*dn, lc = e2*dn;
    lam[(size_t)b*CC + t] = make_float2(lh, lc);
    biasc[(size_t)b*CC + t] = lh*b_h[t] + lc*b_c[t];
}

// Build the 48KB B-tile LDS images.
// Image layout per tile: byte = kk*24576 + n*64 + kpart*16 ; stored fragment (n,kk,kpart)
// holds B[n][ kt*64 + kk*32 + (kpart ^ ((n>>1)&3))*8 .. +8 ]  (bank pre-swizzle).
// wB2: 16 batches x 12 tiles (K=768 dual: k<384 -> lh*wTh, else lc*wTc)
// wP2: 6 tiles (K=384, wTp, no scaling)
__global__ __launch_bounds__(256)
void wcomb_k(const unsigned short* __restrict__ wTh,
             const unsigned short* __restrict__ wTc,
             const unsigned short* __restrict__ wTp,
             const float2* __restrict__ lam,
             unsigned short* __restrict__ wB2,
             unsigned short* __restrict__ wP2)
{
    int idx = blockIdx.x*256 + threadIdx.x;
    const int NB2 = 16*12*3072;
    int kt, f;
    unsigned short* dst;
    int b = 0; bool isP;
    if (idx < NB2) {
        b = idx / (12*3072);
        int rem = idx - b*(12*3072);
        kt = rem / 3072; f = rem - kt*3072;
        dst = wB2 + ((size_t)(b*12 + kt)*3072 + f)*8;
        isP = false;
    } else {
        int j = idx - NB2;
        kt = j / 3072; f = j - kt*3072;
        dst = wP2 + ((size_t)kt*3072 + f)*8;
        isP = true;
    }
    int kk = (f >= 1536) ? 1 : 0;
    int g = f - kk*1536;
    int n = g >> 2, kpart = g & 3;
    int kbase = kt*64 + kk*32 + ((kpart ^ ((n>>1)&3)) << 3);

    bf16x8 v; float s;
    if (isP) {
        v = *(const bf16x8*)(wTp + (size_t)n*CC + kbase);
        s = 1.f;
    } else {
        float2 L = lam[(size_t)b*CC + n];
        if (kbase < 384) { v = *(const bf16x8*)(wTh + (size_t)n*CC + kbase);       s = L.x; }
        else             { v = *(const bf16x8*)(wTc + (size_t)n*CC + kbase - 384); s = L.y; }
    }
    bf16x8 o;
    #pragma unroll
    for (int e = 0; e < 8; ++e) o[e] = (short)f2bf(s * bf2f((unsigned short)v[e]));
    *(bf16x8*)dst = o;
}

__device__ __forceinline__ void issue_tile(const char* g, char* l, int tid) {
    #pragma unroll
    for (int j = 0; j < 6; ++j)
        __builtin_amdgcn_global_load_lds(
            (const __attribute__((address_space(1))) void*)(g + j*8192 + tid*16),
            (__attribute__((address_space(3))) void*)(l + j*8192), 16, 0, 0);
}

// Fused: phase1 A' = [A_shift|A] @ wB2[b] + biasc (12 steps), A'->LDS,
//        phase2 out = A' @ wP2 + b_p (6 steps), rows unpermuted. BK=64.
__global__ __launch_bounds__(512, 2)
void g12_k(const unsigned short* __restrict__ xt,
           const unsigned short* __restrict__ wB2,
           const unsigned short* __restrict__ wP2,
           const float* __restrict__ biasc,
           const float* __restrict__ b_p,
           float* __restrict__ out)
{
    __shared__ char smem[150528];
    char* Asm = smem;                 // 52224: A panel (68 rows x 768B), later A' (64 x 768B)
    char* Bsm = smem + 52224;         // 2 x 49152 B-tile double buffer

    const int tid = threadIdx.x;
    int bid = blockIdx.x;
    bid = (bid & 7)*(NBLK/8) + (bid >> 3);          // XCD-chunked swizzle (784=8*98)
    const int m0 = bid * 64;
    const int b  = m0 / HWW;

    const int lane = tid & 63;
    const int wid  = tid >> 6;
    const int l16  = lane & 15;
    const int lhi  = lane >> 4;
    const int wm = (wid >> 2) * 32;                 // 2 M-waves
    const int wn = (wid & 3) * 96;                  // 4 N-waves

    const char* wb2b = (const char*)wB2 + (size_t)b*12*49152;
    const char* wp2b = (const char*)wP2;
    char* lbase = Bsm + wid*1024;

    // issue tile 0 (overlaps A staging)
    issue_tile(wb2b, lbase, tid);

    // stage A panel: rows m0-2 .. m0+65, oct-XOR swizzle
    #pragma unroll
    for (int it = 0; it < 7; ++it) {
        int s = it*512 + tid;
        if (s < 68*48) {
            int row = s / 48, oct = s - row*48;
            int g = m0 - 2 + row;
            g = g < 0 ? 0 : (g >= MM ? MM-1 : g);
            int4v v = *(const int4v*)(xt + (size_t)g*CC + oct*8);
            *(int4v*)(Asm + row*768 + ((oct ^ (row & 7)) << 4)) = v;
        }
    }

    int rbase[2], hmod[2];
    #pragma unroll
    for (int mi = 0; mi < 2; ++mi) {
        rbase[mi] = wm + mi*16 + l16 + 2;
        hmod[mi]  = (m0 + wm + mi*16 + l16) % HH;
    }
    int Boff[6];
    #pragma unroll
    for (int ni = 0; ni < 6; ++ni) {
        int n = wn + ni*16 + l16;
        Boff[ni] = n*64 + ((lhi ^ ((n >> 1) & 3)) << 4);
    }

    f32x4 acc[2][6];
    #pragma unroll
    for (int mi = 0; mi < 2; ++mi)
        #pragma unroll
        for (int ni = 0; ni < 6; ++ni) acc[mi][ni] = (f32x4)0.f;

    __syncthreads();   // drains tile0 + staging writes (one-time full drain)

    // ---- phase 1a: shifted A, tiles 0..5 ----
    #pragma unroll 2
    for (int kt = 0; kt < 6; ++kt) {
        issue_tile(wb2b + (size_t)(kt+1)*49152, lbase + ((kt+1)&1)*49152, tid);
        asm volatile("s_waitcnt vmcnt(6)" ::: "memory");
        __builtin_amdgcn_s_barrier();
        const char* bbuf = Bsm + (kt&1)*49152;
        #pragma unroll
        for (int kk = 0; kk < 2; ++kk) {
            const int octg = kt*8 + kk*4 + lhi;
            const int d = octg < 6 ? 2 : octg < 18 ? 1 : octg < 30 ? 0 : octg < 42 ? -1 : -2;
            int4v a[2];
            #pragma unroll
            for (int mi = 0; mi < 2; ++mi) {
                int r = rbase[mi] + d;
                int4v v = *(const int4v*)(Asm + r*768 + ((octg ^ (r & 7)) << 4));
                int ok = ((unsigned)(hmod[mi] + d) < (unsigned)HH) ? ~0 : 0;
                a[mi] = v & ok;
            }
            int4v bb[6];
            #pragma unroll
            for (int ni = 0; ni < 6; ++ni)
                bb[ni] = *(const int4v*)(bbuf + kk*24576 + Boff[ni]);
            __builtin_amdgcn_s_setprio(1);
            #pragma unroll
            for (int mi = 0; mi < 2; ++mi)
                #pragma unroll
                for (int ni = 0; ni < 6; ++ni)
                    acc[mi][ni] = __builtin_amdgcn_mfma_f32_16x16x32_bf16(
                        asbf(a[mi]), asbf(bb[ni]), acc[mi][ni], 0, 0, 0);
            __builtin_amdgcn_s_setprio(0);
        }
        __builtin_amdgcn_s_barrier();
    }
    // ---- phase 1b: plain A, tiles 6..11 (tile 12 = first wP2 tile) ----
    #pragma unroll 2
    for (int kt = 6; kt < 12; ++kt) {
        const char* nxt = (kt < 11) ? (wb2b + (size_t)(kt+1)*49152) : wp2b;
        issue_tile(nxt, lbase + ((kt+1)&1)*49152, tid);
        asm volatile("s_waitcnt vmcnt(6)" ::: "memory");
        __builtin_amdgcn_s_barrier();
        const char* bbuf = Bsm + (kt&1)*49152;
        #pragma unroll
        for (int kk = 0; kk < 2; ++kk) {
            const int octg = (kt-6)*8 + kk*4 + lhi;
            int4v a[2];
            #pragma unroll
            for (int mi = 0; mi < 2; ++mi) {
                int r = rbase[mi];
                a[mi] = *(const int4v*)(Asm + r*768 + ((octg ^ (r & 7)) << 4));
            }
            int4v bb[6];
            #pragma unroll
            for (int ni = 0; ni < 6; ++ni)
                bb[ni] = *(const int4v*)(bbuf + kk*24576 + Boff[ni]);
            __builtin_amdgcn_s_setprio(1);
            #pragma unroll
            for (int mi = 0; mi < 2; ++mi)
                #pragma unroll
                for (int ni = 0; ni < 6; ++ni)
                    acc[mi][ni] = __builtin_amdgcn_mfma_f32_16x16x32_bf16(
                        asbf(a[mi]), asbf(bb[ni]), acc[mi][ni], 0, 0, 0);
            __builtin_amdgcn_s_setprio(0);
        }
        __builtin_amdgcn_s_barrier();
    }

    // ---- A' -> LDS (aliases panel region), bf16 ----
    #pragma unroll
    for (int ni = 0; ni < 6; ++ni) {
        int n = wn + ni*16 + l16;
        float bc = biasc[(size_t)b*CC + n];
        int oct = n >> 3, nb = (n & 7)*2;
        #pragma unroll
        for (int mi = 0; mi < 2; ++mi) {
            int row0 = wm + mi*16 + lhi*4;
            #pragma unroll
            for (int j = 0; j < 4; ++j) {
                int row = row0 + j;
                *(unsigned short*)(Asm + row*768 + ((oct ^ (row & 7)) << 4) + nb)
                    = f2bf(acc[mi][ni][j] + bc);
            }
        }
    }
    asm volatile("s_waitcnt lgkmcnt(0)" ::: "memory");
    __builtin_amdgcn_s_barrier();

    #pragma unroll
    for (int mi = 0; mi < 2; ++mi)
        #pragma unroll
        for (int ni = 0; ni < 6; ++ni) acc[mi][ni] = (f32x4)0.f;

    // ---- phase 2: out = A' @ wP2, tiles 12..17 ----
    #pragma unroll 2
    for (int g2 = 0; g2 < 6; ++g2) {
        if (g2 < 5) {
            issue_tile(wp2b + (size_t)(g2+1)*49152, lbase + ((g2+1)&1)*49152, tid);
            asm volatile("s_waitcnt vmcnt(6)" ::: "memory");
        } else {
            asm volatile("s_waitcnt vmcnt(0)" ::: "memory");
        }
        __builtin_amdgcn_s_barrier();
        const char* bbuf = Bsm + (g2&1)*49152;
        #pragma unroll
        for (int kk = 0; kk < 2; ++kk) {
            const int octg = g2*8 + kk*4 + lhi;
            int4v a[2];
            #pragma unroll
            for (int mi = 0; mi < 2; ++mi) {
                int r = wm + mi*16 + l16;
                a[mi] = *(const int4v*)(Asm + r*768 + ((octg ^ (r & 7)) << 4));
            }
            int4v bb[6];
            #pragma unroll
            for (int ni = 0; ni < 6; ++ni)
                bb[ni] = *(const int4v*)(bbuf + kk*24576 + Boff[ni]);
            __builtin_amdgcn_s_setprio(1);
            #pragma unroll
            for (int mi = 0; mi < 2; ++mi)
                #pragma unroll
                for (int ni = 0; ni < 6; ++ni)
                    acc[mi][ni] = __builtin_amdgcn_mfma_f32_16x16x32_bf16(
                        asbf(a[mi]), asbf(bb[ni]), acc[mi][ni], 0, 0, 0);
            __builtin_amdgcn_s_setprio(0);
        }
        __builtin_amdgcn_s_barrier();
    }

    // ---- epilogue: un-permute rows (W-major -> H-major), fp32 out ----
    #pragma unroll
    for (int ni = 0; ni < 6; ++ni) {
        int n = wn + ni*16 + l16;
        float bpv = b_p[n];
        #pragma unroll
        for (int mi = 0; mi < 2; ++mi) {
            #pragma unroll
            for (int j = 0; j < 4; ++j) {
                int r = m0 + wm + mi*16 + lhi*4 + j;
                int tt = r % HWW;
                int hh = tt % HH, ww = tt / HH;
                int ro = (r - tt) + hh*WWD + ww;
                out[(size_t)ro*CC + n] = acc[mi][ni][j] + bpv;
            }
        }
    }
}

extern "C" void kernel_launch(void* const* d_in, const int* in_sizes, int n_in,
                              void* d_out, int out_size, void* d_ws, size_t ws_size,
                              hipStream_t stream)
{
    const float* x    = (const float*)d_in[0];
    const float* w_h  = (const float*)d_in[1];
    const float* b_h  = (const float*)d_in[2];
    const float* w_c  = (const float*)d_in[3];
    const float* b_c  = (const float*)d_in[4];
    const float* w_r1 = (const float*)d_in[5];
    const float* b_r1 = (const float*)d_in[6];
    const float* w_r2 = (const float*)d_in[7];
    const float* b_r2 = (const float*)d_in[8];
    const float* w_p  = (const float*)d_in[9];
    const float* b_p  = (const float*)d_in[10];
    float* out = (float*)d_out;

    char* ws = (char*)d_ws;
    unsigned short* xt  = (unsigned short*)(ws);                 // 38,535,168
    unsigned short* wTh = (unsigned short*)(ws + 38535168);      //    294,912
    unsigned short* wTc = (unsigned short*)(ws + 38830080);      //    294,912
    unsigned short* wTp = (unsigned short*)(ws + 39124992);      //    294,912
    unsigned short* wB2 = (unsigned short*)(ws + 39419904);      //  9,437,184
    unsigned short* wP2 = (unsigned short*)(ws + 48857088);      //    294,912
    float* R            = (float*)(ws + 49152000);               //  1,376,256
    float2* lam         = (float2*)(ws + 50528256);              //     49,152
    float* biasc        = (float*)(ws + 50577408);               //     24,576

    prep_x<<<16*HH, 192, 0, stream>>>(x, xt, R);
    prep_w<<<dim3(12, 12, 3), 256, 0, stream>>>(w_h, w_c, w_p, wTh, wTc, wTp);
    mlp_k<<<16, 384, 0, stream>>>(R, w_h, b_h, w_c, b_c, w_r1, b_r1, w_r2, b_r2, lam, biasc);
    wcomb_k<<<(16*12*3072 + 6*3072)/256, 256, 0, stream>>>(wTh, wTc, wTp, lam, wB2, wP2);
    g12_k<<<NBLK, 512, 0, stream>>>(xt, wB2, wP2, biasc, b_p, out);
}

// Round 6
// 201.872 us; speedup vs baseline: 1.9690x; 1.0698x over previous
//
#include <hip/hip_runtime.h>
#include <hip/hip_bf16.h>

#define HH 56
#define WWD 56
#define CC 384
#define HWW (HH*WWD)         // 3136
#define MM (16*HWW)          // 50176
#define MBPB 25              // M-blocks (of 128) per batch: 25*128 = 3200 >= 3136
#define NBLK3 (16*MBPB)      // 400

typedef __attribute__((ext_vector_type(8))) short bf16x8;
typedef __attribute__((ext_vector_type(4))) int   int4v;
typedef __attribute__((ext_vector_type(4))) float f32x4;

__device__ __forceinline__ unsigned short f2bf(float f) {
    union { float f; unsigned u; } v; v.f = f;
    unsigned r = v.u + 0x7fffu + ((v.u >> 16) & 1u);
    return (unsigned short)(r >> 16);
}
__device__ __forceinline__ float bf2f(unsigned short h) {
    union { unsigned u; float f; } v; v.u = ((unsigned)h) << 16;
    return v.f;
}
__device__ __forceinline__ bf16x8 asbf(int4v v) {
    union { int4v i; bf16x8 b; } u; u.i = v; return u.b;
}

// K-permutation: [d=+2 (48) | +1 (96) | 0 (96) | -1 (96) | -2 (48)], d[c%8]={2,1,0,-1,-2,-1,0,1}
__device__ __forceinline__ int invp(int k) {
    if (k < 48)  return 8*k;
    if (k < 144) { int j = k-48;  return 8*(j>>1) + ((j&1) ? 7 : 1); }
    if (k < 240) { int j = k-144; return 8*(j>>1) + ((j&1) ? 6 : 2); }
    if (k < 336) { int j = k-240; return 8*(j>>1) + ((j&1) ? 5 : 3); }
    return 8*(k-336) + 4;
}
__device__ __forceinline__ int fwdp(int c) {
    int q = c >> 3, s = c & 7;
    switch (s) {
        case 0: return q;
        case 1: return 48 + 2*q;
        case 7: return 49 + 2*q;
        case 2: return 144 + 2*q;
        case 6: return 145 + 2*q;
        case 3: return 240 + 2*q;
        case 5: return 241 + 2*q;
        default: return 336 + q;
    }
}
__device__ __forceinline__ int dcls(int k) {
    return k < 48 ? 2 : k < 144 ? 1 : k < 240 ? 0 : k < 336 ? -1 : -2;
}

// x (B,H,W,C) fp32 -> xt (B,W,H,Cperm) bf16 + row sums R[b*56+h][k']
// coalesced loads, LDS transpose (fwd-perm scatter), coalesced stores
__global__ __launch_bounds__(384)
void prep_x(const float* __restrict__ x, unsigned short* __restrict__ xt,
            float* __restrict__ R)
{
    __shared__ float buf[4][CC];
    int bid = blockIdx.x;            // b*56 + h
    int b = bid / HH, h = bid - b*HH;
    int t = threadIdx.x;
    int wsub = t / 96, q = t - wsub*96;       // quad q -> channels 4q..4q+3
    int kd0 = fwdp(4*q), kd1 = fwdp(4*q+1), kd2 = fwdp(4*q+2), kd3 = fwdp(4*q+3);
    const float* xp = x + ((size_t)bid*WWD)*CC;
    unsigned short* xo = xt + ((size_t)b*HWW + h)*CC + t;
    float rs = 0.f;
    for (int w0 = 0; w0 < WWD; w0 += 4) {
        float4 v = *(const float4*)(xp + (size_t)(w0 + wsub)*CC + 4*q);
        buf[wsub][kd0] = v.x; buf[wsub][kd1] = v.y;
        buf[wsub][kd2] = v.z; buf[wsub][kd3] = v.w;
        __syncthreads();
        #pragma unroll
        for (int i = 0; i < 4; ++i) {
            float fv = buf[i][t];
            rs += fv;
            xo[(size_t)(w0 + i)*HH*CC] = f2bf(fv);
        }
        __syncthreads();
    }
    R[(size_t)bid*CC + t] = rs;
}

// weights fp32 (k,n) -> bf16 transposed (n,k'), rows k-permuted for w_h/w_c
__global__ __launch_bounds__(256)
void prep_w(const float* __restrict__ w_h, const float* __restrict__ w_c,
            const float* __restrict__ w_p,
            unsigned short* __restrict__ wTh, unsigned short* __restrict__ wTc,
            unsigned short* __restrict__ wTp)
{
    __shared__ float tile[32][33];
    int mat = blockIdx.z;
    const float* src = mat == 0 ? w_h : (mat == 1 ? w_c : w_p);
    unsigned short* dst = mat == 0 ? wTh : (mat == 1 ? wTc : wTp);
    int ky = blockIdx.y*32, nx = blockIdx.x*32;
    int tx = threadIdx.x & 31, ty = threadIdx.x >> 5;
    #pragma unroll
    for (int r = ty; r < 32; r += 8) {
        int c = (mat < 2) ? invp(ky + r) : (ky + r);
        tile[r][tx] = src[(size_t)c*CC + nx + tx];
    }
    __syncthreads();
    #pragma unroll
    for (int r = ty; r < 32; r += 8)
        dst[(size_t)(nx + r)*CC + ky + tx] = f2bf(tile[tx][r]);
}

// per-batch: exact means -> a -> GELU MLP -> softmax -> lam + combined bias
__global__ __launch_bounds__(384)
void mlp_k(const float* __restrict__ R,
           const float* __restrict__ w_h, const float* __restrict__ b_h,
           const float* __restrict__ w_c, const float* __restrict__ b_c,
           const float* __restrict__ w_r1, const float* __restrict__ b_r1,
           const float* __restrict__ w_r2, const float* __restrict__ b_r2,
           float2* __restrict__ lam, float* __restrict__ biasc)
{
    __shared__ float mh[CC], mc[CC], aa[CC], r1p[4][96];
    int b = blockIdx.x, t = threadIdx.x;
    const float* Rb = R + (size_t)b*HH*CC;
    float S = 0.f;
    for (int h = 0; h < HH; ++h) S += Rb[(size_t)h*CC + t];
    int d = dcls(t);
    float adj = 0.f;
    if (d == 2)       adj = Rb[0*CC + t] + Rb[1*CC + t];
    else if (d == 1)  adj = Rb[0*CC + t];
    else if (d == -1) adj = Rb[55*CC + t];
    else if (d == -2) adj = Rb[54*CC + t] + Rb[55*CC + t];
    const float inv = 1.f / (float)HWW;
    mh[t] = (S - adj) * inv;
    mc[t] = S * inv;
    __syncthreads();
    float sh = 0.f, sc = 0.f;
    #pragma unroll 4
    for (int k = 0; k < CC; ++k) {
        int c = invp(k);
        sh += mh[k] * w_h[(size_t)c*CC + t];
        sc += mc[k] * w_c[(size_t)c*CC + t];
    }
    aa[t] = 2.f*(sh + b_h[t]) + (sc + b_c[t]);
    __syncthreads();
    {
        int j = t % 96, p = t / 96;
        float s = 0.f;
        for (int k = p*96; k < p*96 + 96; ++k) s += aa[k] * w_r1[(size_t)k*96 + j];
        r1p[p][j] = s;
    }
    __syncthreads();
    if (t < 96) {
        float s = r1p[0][t] + r1p[1][t] + r1p[2][t] + r1p[3][t] + b_r1[t];
        r1p[0][t] = 0.5f*s*(1.f + erff(s*0.70710678118654752f));
    }
    __syncthreads();
    float s0 = b_r2[3*t], s1 = b_r2[3*t+1], s2 = b_r2[3*t+2];
    for (int q = 0; q < 96; ++q) {
        float rv = r1p[0][q];
        const float* wp = w_r2 + (size_t)q*(3*CC) + 3*t;
        s0 += rv*wp[0]; s1 += rv*wp[1]; s2 += rv*wp[2];
    }
    float mx = fmaxf(s0, fmaxf(s1, s2));
    float e0 = expf(s0-mx), e1 = expf(s1-mx), e2 = expf(s2-mx);
    float dn = 1.f/(e0+e1+e2);
    float lh = (e0+e1)*dn, lc = e2*dn;
    lam[(size_t)b*CC + t] = make_float2(lh, lc);
    biasc[(size_t)b*CC + t] = lh*b_h[t] + lc*b_c[t];
}

// Build 24KB (BK=32) B-tile LDS images, bank pre-swizzled.
// tile byte = n*64 + kpart*16 ; frag (n,kpart) holds B[n][kt*32 + (kpart^((n>>1)&3))*8 .. +8]
// wB2: 16 batches x 24 tiles (K=768 dual: k<384 -> lh*wTh, else lc*wTc); wP2: 12 tiles (wTp)
__global__ __launch_bounds__(256)
void wcomb_k(const unsigned short* __restrict__ wTh,
             const unsigned short* __restrict__ wTc,
             const unsigned short* __restrict__ wTp,
             const float2* __restrict__ lam,
             unsigned short* __restrict__ wB2,
             unsigned short* __restrict__ wP2)
{
    int idx = blockIdx.x*256 + threadIdx.x;
    const int NB2 = 16*24*1536;
    int kt, f, b = 0; bool isP;
    unsigned short* dst;
    if (idx < NB2) {
        b = idx / (24*1536);
        int rem = idx - b*(24*1536);
        kt = rem / 1536; f = rem - kt*1536;
        dst = wB2 + ((size_t)(b*24 + kt)*1536 + f)*8;
        isP = false;
    } else {
        int j = idx - NB2;
        kt = j / 1536; f = j - kt*1536;
        dst = wP2 + ((size_t)kt*1536 + f)*8;
        isP = true;
    }
    int n = f >> 2, kpart = f & 3;
    int kbase = kt*32 + ((kpart ^ ((n>>1)&3)) << 3);

    bf16x8 v; float s;
    if (isP) {
        v = *(const bf16x8*)(wTp + (size_t)n*CC + kbase);
        s = 1.f;
    } else {
        float2 L = lam[(size_t)b*CC + n];
        if (kbase < 384) { v = *(const bf16x8*)(wTh + (size_t)n*CC + kbase);       s = L.x; }
        else             { v = *(const bf16x8*)(wTc + (size_t)n*CC + kbase - 384); s = L.y; }
    }
    bf16x8 o;
    #pragma unroll
    for (int e = 0; e < 8; ++e) o[e] = (short)f2bf(s * bf2f((unsigned short)v[e]));
    *(bf16x8*)dst = o;
}

// dest (per-wave uniform) l: lds addr = l + j*8192 + lane*16
// src per-lane: g + j*8192 + tid*16 = g + j*8192 + wid*1024 + lane*16
// caller must pass l including wid*1024 so src/dest offsets match.
__device__ __forceinline__ void issue_tile3(const char* g, char* l, int tid) {
    #pragma unroll
    for (int j = 0; j < 3; ++j)
        __builtin_amdgcn_global_load_lds(
            (const __attribute__((address_space(1))) void*)(g + j*8192 + tid*16),
            (__attribute__((address_space(3))) void*)(l + j*8192), 16, 0, 0);
}

// Fused M=128 (batch-local, padded): phase1 A' = [A_shift|A] @ wB2[b] + biasc (24 BK=32 steps),
// A'->LDS, phase2 out = A' @ wP2 + b_p (12 steps), rows unpermuted.
__global__ __launch_bounds__(512, 2)
void g12_k(const unsigned short* __restrict__ xt,
           const unsigned short* __restrict__ wB2,
           const unsigned short* __restrict__ wP2,
           const float* __restrict__ biasc,
           const float* __restrict__ b_p,
           float* __restrict__ out)
{
    __shared__ char smem[150528];
    char* Asm = smem;                 // 101376: A panel 132 rows x 768B; later A' 128 x 768B
    char* Bsm = smem + 101376;        // 2 x 24576 B-tile double buffer

    const int tid = threadIdx.x;
    int bid = blockIdx.x;
    bid = (bid & 7)*(NBLK3/8) + (bid >> 3);       // XCD-chunked swizzle (400=8*50)
    const int b  = bid / MBPB;                    // batch
    const int m0 = (bid - b*MBPB) * 128;          // batch-local row base (0..3072)
    const size_t gbase = (size_t)b * HWW;

    const int lane = tid & 63;
    const int wid  = tid >> 6;
    const int l16  = lane & 15;
    const int lhi  = lane >> 4;
    const int wm = (wid >> 2) * 64;               // 2 M-waves, 64 rows each
    const int wn = (wid & 3) * 96;                // 4 N-waves, 96 cols each

    const char* wb2b = (const char*)wB2 + (size_t)b*24*24576;
    const char* wp2b = (const char*)wP2;
    char* lbase = Bsm + wid*1024;                 // per-wave dest slice

    // issue tile 0 (overlaps A staging)
    issue_tile3(wb2b, lbase, tid);

    // stage A panel: batch-local rows m0-2 .. m0+129 (clamped in-batch), oct-XOR swizzle
    #pragma unroll
    for (int it = 0; it < 13; ++it) {
        int s = it*512 + tid;
        if (s < 132*48) {
            int row = s / 48, oct = s - row*48;
            int g = m0 - 2 + row;
            g = g < 0 ? 0 : (g >= HWW ? HWW-1 : g);
            int4v v = *(const int4v*)(xt + (gbase + g)*CC + oct*8);
            *(int4v*)(Asm + row*768 + ((oct ^ (row & 7)) << 4)) = v;
        }
    }

    int rbase[4], hmod[4];
    #pragma unroll
    for (int mi = 0; mi < 4; ++mi) {
        rbase[mi] = wm + mi*16 + l16 + 2;
        hmod[mi]  = (m0 + wm + mi*16 + l16) % HH;
    }
    int Boff[6];
    #pragma unroll
    for (int ni = 0; ni < 6; ++ni) {
        int n = wn + ni*16 + l16;
        Boff[ni] = n*64 + ((lhi ^ ((n >> 1) & 3)) << 4);
    }

    f32x4 acc[4][6];
    #pragma unroll
    for (int mi = 0; mi < 4; ++mi)
        #pragma unroll
        for (int ni = 0; ni < 6; ++ni) acc[mi][ni] = (f32x4)0.f;

    __syncthreads();   // drains tile0 + A staging (one-time full drain)

    // ---- phase 1a: shifted A, tiles 0..11 ----
    #pragma unroll 2
    for (int kt = 0; kt < 12; ++kt) {
        issue_tile3(wb2b + (size_t)(kt+1)*24576, lbase + ((kt+1)&1)*24576, tid);
        asm volatile("s_waitcnt vmcnt(3)" ::: "memory");
        __builtin_amdgcn_s_barrier();
        const char* bbuf = Bsm + (kt&1)*24576;
        const int octg = kt*4 + lhi;
        const int d = octg < 6 ? 2 : octg < 18 ? 1 : octg < 30 ? 0 : octg < 42 ? -1 : -2;
        int4v a[4];
        #pragma unroll
        for (int mi = 0; mi < 4; ++mi) {
            int r = rbase[mi] + d;
            int4v v = *(const int4v*)(Asm + r*768 + ((octg ^ (r & 7)) << 4));
            int ok = ((unsigned)(hmod[mi] + d) < (unsigned)HH) ? ~0 : 0;
            a[mi] = v & ok;
        }
        int4v bb[6];
        #pragma unroll
        for (int ni = 0; ni < 6; ++ni)
            bb[ni] = *(const int4v*)(bbuf + Boff[ni]);
        __builtin_amdgcn_s_setprio(1);
        #pragma unroll
        for (int mi = 0; mi < 4; ++mi)
            #pragma unroll
            for (int ni = 0; ni < 6; ++ni)
                acc[mi][ni] = __builtin_amdgcn_mfma_f32_16x16x32_bf16(
                    asbf(a[mi]), asbf(bb[ni]), acc[mi][ni], 0, 0, 0);
        __builtin_amdgcn_s_setprio(0);
        __builtin_amdgcn_s_barrier();
    }
    // ---- phase 1b: plain A, tiles 12..23 (next after 23 = wP2 tile 0) ----
    #pragma unroll 2
    for (int kt = 12; kt < 24; ++kt) {
        const char* nxt = (kt < 23) ? (wb2b + (size_t)(kt+1)*24576) : wp2b;
        issue_tile3(nxt, lbase + ((kt+1)&1)*24576, tid);
        asm volatile("s_waitcnt vmcnt(3)" ::: "memory");
        __builtin_amdgcn_s_barrier();
        const char* bbuf = Bsm + (kt&1)*24576;
        const int octg = (kt-12)*4 + lhi;
        int4v a[4];
        #pragma unroll
        for (int mi = 0; mi < 4; ++mi) {
            int r = rbase[mi];
            a[mi] = *(const int4v*)(Asm + r*768 + ((octg ^ (r & 7)) << 4));
        }
        int4v bb[6];
        #pragma unroll
        for (int ni = 0; ni < 6; ++ni)
            bb[ni] = *(const int4v*)(bbuf + Boff[ni]);
        __builtin_amdgcn_s_setprio(1);
        #pragma unroll
        for (int mi = 0; mi < 4; ++mi)
            #pragma unroll
            for (int ni = 0; ni < 6; ++ni)
                acc[mi][ni] = __builtin_amdgcn_mfma_f32_16x16x32_bf16(
                    asbf(a[mi]), asbf(bb[ni]), acc[mi][ni], 0, 0, 0);
        __builtin_amdgcn_s_setprio(0);
        __builtin_amdgcn_s_barrier();
    }

    // ---- A' -> LDS (rows 0..127 of panel region), bf16 ----
    #pragma unroll
    for (int ni = 0; ni < 6; ++ni) {
        int n = wn + ni*16 + l16;
        float bc = biasc[(size_t)b*CC + n];
        int oct = n >> 3, nb = (n & 7)*2;
        #pragma unroll
        for (int mi = 0; mi < 4; ++mi) {
            int row0 = wm + mi*16 + lhi*4;
            #pragma unroll
            for (int j = 0; j < 4; ++j) {
                int row = row0 + j;
                *(unsigned short*)(Asm + row*768 + ((oct ^ (row & 7)) << 4) + nb)
                    = f2bf(acc[mi][ni][j] + bc);
            }
        }
    }
    asm volatile("s_waitcnt lgkmcnt(0)" ::: "memory");
    __builtin_amdgcn_s_barrier();

    #pragma unroll
    for (int mi = 0; mi < 4; ++mi)
        #pragma unroll
        for (int ni = 0; ni < 6; ++ni) acc[mi][ni] = (f32x4)0.f;

    // ---- phase 2: out = A' @ wP2, tiles 0..11 ----
    #pragma unroll 2
    for (int g2 = 0; g2 < 12; ++g2) {
        if (g2 < 11) {
            issue_tile3(wp2b + (size_t)(g2+1)*24576, lbase + ((g2+1)&1)*24576, tid);
            asm volatile("s_waitcnt vmcnt(3)" ::: "memory");
        } else {
            asm volatile("s_waitcnt vmcnt(0)" ::: "memory");
        }
        __builtin_amdgcn_s_barrier();
        const char* bbuf = Bsm + (g2&1)*24576;
        const int octg = g2*4 + lhi;
        int4v a[4];
        #pragma unroll
        for (int mi = 0; mi < 4; ++mi) {
            int r = wm + mi*16 + l16;
            a[mi] = *(const int4v*)(Asm + r*768 + ((octg ^ (r & 7)) << 4));
        }
        int4v bb[6];
        #pragma unroll
        for (int ni = 0; ni < 6; ++ni)
            bb[ni] = *(const int4v*)(bbuf + Boff[ni]);
        __builtin_amdgcn_s_setprio(1);
        #pragma unroll
        for (int mi = 0; mi < 4; ++mi)
            #pragma unroll
            for (int ni = 0; ni < 6; ++ni)
                acc[mi][ni] = __builtin_amdgcn_mfma_f32_16x16x32_bf16(
                    asbf(a[mi]), asbf(bb[ni]), acc[mi][ni], 0, 0, 0);
        __builtin_amdgcn_s_setprio(0);
        __builtin_amdgcn_s_barrier();
    }

    // ---- epilogue: un-permute rows (W-major -> H-major), fp32 out, skip pad rows ----
    #pragma unroll
    for (int ni = 0; ni < 6; ++ni) {
        int n = wn + ni*16 + l16;
        float bpv = b_p[n];
        #pragma unroll
        for (int mi = 0; mi < 4; ++mi) {
            #pragma unroll
            for (int j = 0; j < 4; ++j) {
                int rl = m0 + wm + mi*16 + lhi*4 + j;   // batch-local token (w*56+h)
                if (rl < HWW) {
                    int hh = rl % HH, ww = rl / HH;
                    out[(gbase + hh*WWD + ww)*CC + n] = acc[mi][ni][j] + bpv;
                }
            }
        }
    }
}

extern "C" void kernel_launch(void* const* d_in, const int* in_sizes, int n_in,
                              void* d_out, int out_size, void* d_ws, size_t ws_size,
                              hipStream_t stream)
{
    const float* x    = (const float*)d_in[0];
    const float* w_h  = (const float*)d_in[1];
    const float* b_h  = (const float*)d_in[2];
    const float* w_c  = (const float*)d_in[3];
    const float* b_c  = (const float*)d_in[4];
    const float* w_r1 = (const float*)d_in[5];
    const float* b_r1 = (const float*)d_in[6];
    const float* w_r2 = (const float*)d_in[7];
    const float* b_r2 = (const float*)d_in[8];
    const float* w_p  = (const float*)d_in[9];
    const float* b_p  = (const float*)d_in[10];
    float* out = (float*)d_out;

    char* ws = (char*)d_ws;
    unsigned short* xt  = (unsigned short*)(ws);                 // 38,535,168
    unsigned short* wTh = (unsigned short*)(ws + 38535168);      //    294,912
    unsigned short* wTc = (unsigned short*)(ws + 38830080);      //    294,912
    unsigned short* wTp = (unsigned short*)(ws + 39124992);      //    294,912
    unsigned short* wB2 = (unsigned short*)(ws + 39419904);      //  9,437,184
    unsigned short* wP2 = (unsigned short*)(ws + 48857088);      //    294,912
    float* R            = (float*)(ws + 49152000);               //  1,376,256
    float2* lam         = (float2*)(ws + 50528256);              //     49,152
    float* biasc        = (float*)(ws + 50577408);               //     24,576

    prep_x<<<16*HH, 384, 0, stream>>>(x, xt, R);
    prep_w<<<dim3(12, 12, 3), 256, 0, stream>>>(w_h, w_c, w_p, wTh, wTc, wTp);
    mlp_k<<<16, 384, 0, stream>>>(R, w_h, b_h, w_c, b_c, w_r1, b_r1, w_r2, b_r2, lam, biasc);
    wcomb_k<<<(16*24*1536 + 12*1536)/256, 256, 0, stream>>>(wTh, wTc, wTp, lam, wB2, wP2);
    g12_k<<<NBLK3, 512, 0, stream>>>(xt, wB2, wP2, biasc, b_p, out);
}

// Round 7
// 181.832 us; speedup vs baseline: 2.1860x; 1.1102x over previous
//
#include <hip/hip_runtime.h>
#include <hip/hip_bf16.h>

#define HH 56
#define WWD 56
#define CC 384
#define HWW (HH*WWD)         // 3136
#define MM (16*HWW)          // 50176
#define MBPB 25              // M-blocks (of 128) per batch
#define NBLK3 (16*MBPB)      // 400
#define WB_BSTRIDE (24*24576) // 589824 bytes per batch in wB3

typedef __attribute__((ext_vector_type(8))) short bf16x8;
typedef __attribute__((ext_vector_type(4))) int   int4v;
typedef __attribute__((ext_vector_type(4))) float f32x4;

__device__ __forceinline__ unsigned short f2bf(float f) {
    union { float f; unsigned u; } v; v.f = f;
    unsigned r = v.u + 0x7fffu + ((v.u >> 16) & 1u);
    return (unsigned short)(r >> 16);
}
__device__ __forceinline__ float bf2f(unsigned short h) {
    union { unsigned u; float f; } v; v.u = ((unsigned)h) << 16;
    return v.f;
}
__device__ __forceinline__ bf16x8 asbf(int4v v) {
    union { int4v i; bf16x8 b; } u; u.i = v; return u.b;
}

// K-permutation: [d=+2 (48) | +1 (96) | 0 (96) | -1 (96) | -2 (48)], d[c%8]={2,1,0,-1,-2,-1,0,1}
__device__ __forceinline__ int invp(int k) {
    if (k < 48)  return 8*k;
    if (k < 144) { int j = k-48;  return 8*(j>>1) + ((j&1) ? 7 : 1); }
    if (k < 240) { int j = k-144; return 8*(j>>1) + ((j&1) ? 6 : 2); }
    if (k < 336) { int j = k-240; return 8*(j>>1) + ((j&1) ? 5 : 3); }
    return 8*(k-336) + 4;
}
__device__ __forceinline__ int fwdp(int c) {
    int q = c >> 3, s = c & 7;
    switch (s) {
        case 0: return q;
        case 1: return 48 + 2*q;
        case 7: return 49 + 2*q;
        case 2: return 144 + 2*q;
        case 6: return 145 + 2*q;
        case 3: return 240 + 2*q;
        case 5: return 241 + 2*q;
        default: return 336 + q;
    }
}
__device__ __forceinline__ int dcls(int k) {
    return k < 48 ? 2 : k < 144 ? 1 : k < 240 ? 0 : k < 336 ? -1 : -2;
}

// x (B,H,W,C) fp32 -> xt (B,W,H,Cperm) bf16 + row sums R[b*56+h][k']
__global__ __launch_bounds__(384)
void prep_x(const float* __restrict__ x, unsigned short* __restrict__ xt,
            float* __restrict__ R)
{
    __shared__ float buf[4][CC];
    int bid = blockIdx.x;            // b*56 + h
    int b = bid / HH, h = bid - b*HH;
    int t = threadIdx.x;
    int wsub = t / 96, q = t - wsub*96;       // quad q -> channels 4q..4q+3
    int kd0 = fwdp(4*q), kd1 = fwdp(4*q+1), kd2 = fwdp(4*q+2), kd3 = fwdp(4*q+3);
    const float* xp = x + ((size_t)bid*WWD)*CC;
    unsigned short* xo = xt + ((size_t)b*HWW + h)*CC + t;
    float rs = 0.f;
    for (int w0 = 0; w0 < WWD; w0 += 4) {
        float4 v = *(const float4*)(xp + (size_t)(w0 + wsub)*CC + 4*q);
        buf[wsub][kd0] = v.x; buf[wsub][kd1] = v.y;
        buf[wsub][kd2] = v.z; buf[wsub][kd3] = v.w;
        __syncthreads();
        #pragma unroll
        for (int i = 0; i < 4; ++i) {
            float fv = buf[i][t];
            rs += fv;
            xo[(size_t)(w0 + i)*HH*CC] = f2bf(fv);
        }
        __syncthreads();
    }
    R[(size_t)bid*CC + t] = rs;
}

// per-batch: exact means (border-corrected) -> a -> GELU MLP -> softmax -> lam + combined bias
__global__ __launch_bounds__(384)
void mlp_k(const float* __restrict__ R,
           const float* __restrict__ w_h, const float* __restrict__ b_h,
           const float* __restrict__ w_c, const float* __restrict__ b_c,
           const float* __restrict__ w_r1, const float* __restrict__ b_r1,
           const float* __restrict__ w_r2, const float* __restrict__ b_r2,
           float2* __restrict__ lam, float* __restrict__ biasc)
{
    __shared__ float mh[CC], mc[CC], aa[CC], r1p[4][96];
    int b = blockIdx.x, t = threadIdx.x;
    const float* Rb = R + (size_t)b*HH*CC;
    float S = 0.f;
    for (int h = 0; h < HH; ++h) S += Rb[(size_t)h*CC + t];
    int d = dcls(t);
    float adj = 0.f;
    if (d == 2)       adj = Rb[0*CC + t] + Rb[1*CC + t];
    else if (d == 1)  adj = Rb[0*CC + t];
    else if (d == -1) adj = Rb[55*CC + t];
    else if (d == -2) adj = Rb[54*CC + t] + Rb[55*CC + t];
    const float inv = 1.f / (float)HWW;
    mh[t] = (S - adj) * inv;
    mc[t] = S * inv;
    __syncthreads();
    float sh = 0.f, sc = 0.f;
    #pragma unroll 4
    for (int k = 0; k < CC; ++k) {
        int c = invp(k);
        sh += mh[k] * w_h[(size_t)c*CC + t];
        sc += mc[k] * w_c[(size_t)c*CC + t];
    }
    aa[t] = 2.f*(sh + b_h[t]) + (sc + b_c[t]);
    __syncthreads();
    {
        int j = t % 96, p = t / 96;
        float s = 0.f;
        for (int k = p*96; k < p*96 + 96; ++k) s += aa[k] * w_r1[(size_t)k*96 + j];
        r1p[p][j] = s;
    }
    __syncthreads();
    if (t < 96) {
        float s = r1p[0][t] + r1p[1][t] + r1p[2][t] + r1p[3][t] + b_r1[t];
        r1p[0][t] = 0.5f*s*(1.f + erff(s*0.70710678118654752f));
    }
    __syncthreads();
    float s0 = b_r2[3*t], s1 = b_r2[3*t+1], s2 = b_r2[3*t+2];
    for (int q = 0; q < 96; ++q) {
        float rv = r1p[0][q];
        const float* wp = w_r2 + (size_t)q*(3*CC) + 3*t;
        s0 += rv*wp[0]; s1 += rv*wp[1]; s2 += rv*wp[2];
    }
    float mx = fmaxf(s0, fmaxf(s1, s2));
    float e0 = expf(s0-mx), e1 = expf(s1-mx), e2 = expf(s2-mx);
    float dn = 1.f/(e0+e1+e2);
    float lh = (e0+e1)*dn, lc = e2*dn;
    lam[(size_t)b*CC + t] = make_float2(lh, lc);
    biasc[(size_t)b*CC + t] = lh*b_h[t] + lc*b_c[t];
}

// Build register-fragment-ordered B images directly from raw fp32 weights.
// Frag (kt, wnx, ni, lane): 16B = B[n][k0..k0+7], n = wnx*96+ni*16+(lane&15),
// k0 = kt*32+(lane>>4)*8. Tile = 24576 B. wB3: per-batch lam-scaled dual [w_h|w_c]
// (K=768, rows k-permuted); wP3: w_p (K=384, natural order).
__global__ __launch_bounds__(256)
void wcomb2(const float* __restrict__ w_h, const float* __restrict__ w_c,
            const float* __restrict__ w_p, const float2* __restrict__ lam,
            char* __restrict__ wB3, char* __restrict__ wP3)
{
    int idx = blockIdx.x*256 + threadIdx.x;
    if (idx < 24*1536) {
        int kt = idx / 1536, f = idx - kt*1536;
        int wnx = f / 384, r = f - wnx*384;
        int ni = r / 64, lane = r - ni*64;
        int n = wnx*96 + ni*16 + (lane & 15);
        int k0 = kt*32 + ((lane >> 4) << 3);
        bool hpart = k0 < 384;
        const float* src = hpart ? w_h : w_c;
        int koff = hpart ? k0 : (k0 - 384);
        float vals[8];
        #pragma unroll
        for (int e = 0; e < 8; ++e) vals[e] = src[(size_t)invp(koff + e)*CC + n];
        size_t foff = (size_t)kt*24576 + wnx*6144 + ni*1024 + lane*16;
        for (int b = 0; b < 16; ++b) {
            float2 L = lam[(size_t)b*CC + n];
            float s = hpart ? L.x : L.y;
            bf16x8 o;
            #pragma unroll
            for (int e = 0; e < 8; ++e) o[e] = (short)f2bf(s * vals[e]);
            *(bf16x8*)(wB3 + (size_t)b*WB_BSTRIDE + foff) = o;
        }
    } else {
        int j = idx - 24*1536;
        int kt = j / 1536, f = j - kt*1536;
        int wnx = f / 384, r = f - wnx*384;
        int ni = r / 64, lane = r - ni*64;
        int n = wnx*96 + ni*16 + (lane & 15);
        int k0 = kt*32 + ((lane >> 4) << 3);
        bf16x8 o;
        #pragma unroll
        for (int e = 0; e < 8; ++e) o[e] = (short)f2bf(w_p[(size_t)(k0 + e)*CC + n]);
        *(bf16x8*)(wP3 + (size_t)kt*24576 + wnx*6144 + ni*1024 + lane*16) = o;
    }
}

// Fused, barrier-free K-loop: A panel in LDS (read-only), B streamed to registers
// in MFMA fragment order with depth-2 rotating prefetch. Only 3 barriers total.
__global__ __launch_bounds__(512, 2)
void g12r(const unsigned short* __restrict__ xt,
          const char* __restrict__ wB3,
          const char* __restrict__ wP3,
          const float* __restrict__ biasc,
          const float* __restrict__ b_p,
          float* __restrict__ out)
{
    __shared__ char Asm[132*768];   // 101,376 B: A panel (halo rows m0-2..m0+129); later A'

    const int tid = threadIdx.x;
    int bid = blockIdx.x;
    bid = (bid & 7)*(NBLK3/8) + (bid >> 3);       // XCD-chunked swizzle (400=8*50)
    const int b  = bid / MBPB;
    const int m0 = (bid - b*MBPB) * 128;          // batch-local row base
    const size_t gbase = (size_t)b * HWW;

    const int lane = tid & 63;
    const int wid  = tid >> 6;
    const int l16  = lane & 15;
    const int lhi  = lane >> 4;
    const int wm  = (wid >> 2) * 64;              // 2 M-waves
    const int wnx = wid & 3;                      // 4 N-waves
    const int wn  = wnx * 96;

    const char* bptr1 = wB3 + (size_t)b*WB_BSTRIDE + wnx*6144 + lane*16;
    const char* bptr2 = wP3 + wnx*6144 + lane*16;

    // prologue B loads: tiles 0,1 into sets 0,1 (first in VMEM queue)
    int4v bb[3][6];
    #pragma unroll
    for (int ni = 0; ni < 6; ++ni)
        bb[0][ni] = *(const int4v*)(bptr1 + ni*1024);
    #pragma unroll
    for (int ni = 0; ni < 6; ++ni)
        bb[1][ni] = *(const int4v*)(bptr1 + 24576 + ni*1024);

    // stage A panel (reg-staged, oct-XOR swizzle), nontemporal reads
    #pragma unroll
    for (int it = 0; it < 13; ++it) {
        int s = it*512 + tid;
        if (s < 132*48) {
            int row = s / 48, oct = s - row*48;
            int g = m0 - 2 + row;
            g = g < 0 ? 0 : (g >= HWW ? HWW-1 : g);
            int4v v = __builtin_nontemporal_load(
                (const int4v*)(xt + (gbase + g)*CC + oct*8));
            *(int4v*)(Asm + row*768 + ((oct ^ (row & 7)) << 4)) = v;
        }
    }

    int rbase[4], hmod[4];
    #pragma unroll
    for (int mi = 0; mi < 4; ++mi) {
        rbase[mi] = wm + mi*16 + l16 + 2;
        hmod[mi]  = (m0 + wm + mi*16 + l16) % HH;
    }

    f32x4 acc[4][6];
    #pragma unroll
    for (int mi = 0; mi < 4; ++mi)
        #pragma unroll
        for (int ni = 0; ni < 6; ++ni) acc[mi][ni] = (f32x4)0.f;

    __syncthreads();   // A panel ready (also drains prologue B, one-time)

    // ---- phase 1: 24 BK=32 steps, no barriers, rotating depth-2 B prefetch ----
    #pragma unroll
    for (int kt = 0; kt < 24; ++kt) {
        const char* nx = (kt + 2 < 24) ? (bptr1 + (size_t)(kt+2)*24576)
                                       : (bptr2 + (size_t)(kt+2-24)*24576);
        #pragma unroll
        for (int ni = 0; ni < 6; ++ni)
            bb[(kt+2)%3][ni] = *(const int4v*)(nx + ni*1024);

        int4v a[4];
        if (kt < 12) {
            const int octg = kt*4 + lhi;
            const int d = octg < 6 ? 2 : octg < 18 ? 1 : octg < 30 ? 0 : octg < 42 ? -1 : -2;
            #pragma unroll
            for (int mi = 0; mi < 4; ++mi) {
                int r = rbase[mi] + d;
                int4v v = *(const int4v*)(Asm + r*768 + ((octg ^ (r & 7)) << 4));
                int ok = ((unsigned)(hmod[mi] + d) < (unsigned)HH) ? ~0 : 0;
                a[mi] = v & ok;
            }
        } else {
            const int octg = (kt-12)*4 + lhi;
            #pragma unroll
            for (int mi = 0; mi < 4; ++mi) {
                int r = rbase[mi];
                a[mi] = *(const int4v*)(Asm + r*768 + ((octg ^ (r & 7)) << 4));
            }
        }
        __builtin_amdgcn_s_setprio(1);
        #pragma unroll
        for (int mi = 0; mi < 4; ++mi)
            #pragma unroll
            for (int ni = 0; ni < 6; ++ni)
                acc[mi][ni] = __builtin_amdgcn_mfma_f32_16x16x32_bf16(
                    asbf(a[mi]), asbf(bb[kt%3][ni]), acc[mi][ni], 0, 0, 0);
        __builtin_amdgcn_s_setprio(0);
    }

    __syncthreads();   // all waves done reading A panel

    // ---- A' -> LDS (rows 0..127), bf16, + biasc ----
    #pragma unroll
    for (int ni = 0; ni < 6; ++ni) {
        int n = wn + ni*16 + l16;
        float bc = biasc[(size_t)b*CC + n];
        int oct = n >> 3, nb = (n & 7)*2;
        #pragma unroll
        for (int mi = 0; mi < 4; ++mi) {
            int row0 = wm + mi*16 + lhi*4;
            #pragma unroll
            for (int j = 0; j < 4; ++j) {
                int row = row0 + j;
                *(unsigned short*)(Asm + row*768 + ((oct ^ (row & 7)) << 4) + nb)
                    = f2bf(acc[mi][ni][j] + bc);
            }
        }
    }
    __syncthreads();   // A' visible to all

    #pragma unroll
    for (int mi = 0; mi < 4; ++mi)
        #pragma unroll
        for (int ni = 0; ni < 6; ++ni) acc[mi][ni] = (f32x4)0.f;

    // ---- phase 2: 12 steps, barrier-free; pipeline continues across handoff ----
    #pragma unroll
    for (int g2 = 0; g2 < 12; ++g2) {
        if (g2 + 2 < 12) {
            #pragma unroll
            for (int ni = 0; ni < 6; ++ni)
                bb[(g2+2)%3][ni] = *(const int4v*)(bptr2 + (size_t)(g2+2)*24576 + ni*1024);
        }
        const int octg = g2*4 + lhi;
        int4v a[4];
        #pragma unroll
        for (int mi = 0; mi < 4; ++mi) {
            int r = wm + mi*16 + l16;
            a[mi] = *(const int4v*)(Asm + r*768 + ((octg ^ (r & 7)) << 4));
        }
        __builtin_amdgcn_s_setprio(1);
        #pragma unroll
        for (int mi = 0; mi < 4; ++mi)
            #pragma unroll
            for (int ni = 0; ni < 6; ++ni)
                acc[mi][ni] = __builtin_amdgcn_mfma_f32_16x16x32_bf16(
                    asbf(a[mi]), asbf(bb[g2%3][ni]), acc[mi][ni], 0, 0, 0);
        __builtin_amdgcn_s_setprio(0);
    }

    // ---- epilogue: un-permute rows (W-major -> H-major), fp32 nontemporal ----
    #pragma unroll
    for (int ni = 0; ni < 6; ++ni) {
        int n = wn + ni*16 + l16;
        float bpv = b_p[n];
        #pragma unroll
        for (int mi = 0; mi < 4; ++mi) {
            #pragma unroll
            for (int j = 0; j < 4; ++j) {
                int rl = m0 + wm + mi*16 + lhi*4 + j;
                if (rl < HWW) {
                    int hh = rl % HH, ww = rl / HH;
                    __builtin_nontemporal_store(acc[mi][ni][j] + bpv,
                        out + (gbase + (size_t)(hh*WWD + ww))*CC + n);
                }
            }
        }
    }
}

extern "C" void kernel_launch(void* const* d_in, const int* in_sizes, int n_in,
                              void* d_out, int out_size, void* d_ws, size_t ws_size,
                              hipStream_t stream)
{
    const float* x    = (const float*)d_in[0];
    const float* w_h  = (const float*)d_in[1];
    const float* b_h  = (const float*)d_in[2];
    const float* w_c  = (const float*)d_in[3];
    const float* b_c  = (const float*)d_in[4];
    const float* w_r1 = (const float*)d_in[5];
    const float* b_r1 = (const float*)d_in[6];
    const float* w_r2 = (const float*)d_in[7];
    const float* b_r2 = (const float*)d_in[8];
    const float* w_p  = (const float*)d_in[9];
    const float* b_p  = (const float*)d_in[10];
    float* out = (float*)d_out;

    char* ws = (char*)d_ws;
    unsigned short* xt  = (unsigned short*)(ws);                 // 38,535,168
    char* wB3           = ws + 38535168;                         //  9,437,184
    char* wP3           = ws + 47972352;                         //    294,912
    float* R            = (float*)(ws + 48267264);               //  1,376,256
    float2* lam         = (float2*)(ws + 49643520);              //     49,152
    float* biasc        = (float*)(ws + 49692672);               //     24,576

    prep_x<<<16*HH, 384, 0, stream>>>(x, xt, R);
    mlp_k<<<16, 384, 0, stream>>>(R, w_h, b_h, w_c, b_c, w_r1, b_r1, w_r2, b_r2, lam, biasc);
    wcomb2<<<(24*1536 + 12*1536)/256, 256, 0, stream>>>(w_h, w_c, w_p, lam, wB3, wP3);
    g12r<<<NBLK3, 512, 0, stream>>>(xt, wB3, wP3, biasc, b_p, out);
}

// Round 8
// 124.318 us; speedup vs baseline: 3.1973x; 1.4626x over previous
//
#include <hip/hip_runtime.h>
#include <hip/hip_bf16.h>

#define HH 56
#define WWD 56
#define CC 384
#define HWW (HH*WWD)         // 3136
#define MM (16*HWW)          // 50176
#define MBPB 25              // M-blocks (of 128) per batch
#define NBLK3 (16*MBPB)      // 400
#define WB_BSTRIDE (24*24576) // 589824 bytes per batch in wB3

typedef __attribute__((ext_vector_type(8))) short bf16x8;
typedef __attribute__((ext_vector_type(4))) int   int4v;
typedef __attribute__((ext_vector_type(4))) float f32x4;

__device__ __forceinline__ unsigned short f2bf(float f) {
    union { float f; unsigned u; } v; v.f = f;
    unsigned r = v.u + 0x7fffu + ((v.u >> 16) & 1u);
    return (unsigned short)(r >> 16);
}
__device__ __forceinline__ float bf2f(unsigned short h) {
    union { unsigned u; float f; } v; v.u = ((unsigned)h) << 16;
    return v.f;
}
__device__ __forceinline__ bf16x8 asbf(int4v v) {
    union { int4v i; bf16x8 b; } u; u.i = v; return u.b;
}

// K-permutation: [d=+2 (48) | +1 (96) | 0 (96) | -1 (96) | -2 (48)], d[c%8]={2,1,0,-1,-2,-1,0,1}
__device__ __forceinline__ int invp(int k) {
    if (k < 48)  return 8*k;
    if (k < 144) { int j = k-48;  return 8*(j>>1) + ((j&1) ? 7 : 1); }
    if (k < 240) { int j = k-144; return 8*(j>>1) + ((j&1) ? 6 : 2); }
    if (k < 336) { int j = k-240; return 8*(j>>1) + ((j&1) ? 5 : 3); }
    return 8*(k-336) + 4;
}
__device__ __forceinline__ int fwdp(int c) {
    int q = c >> 3, s = c & 7;
    switch (s) {
        case 0: return q;
        case 1: return 48 + 2*q;
        case 7: return 49 + 2*q;
        case 2: return 144 + 2*q;
        case 6: return 145 + 2*q;
        case 3: return 240 + 2*q;
        case 5: return 241 + 2*q;
        default: return 336 + q;
    }
}
__device__ __forceinline__ int dcls(int k) {
    return k < 48 ? 2 : k < 144 ? 1 : k < 240 ? 0 : k < 336 ? -1 : -2;
}

// x (B,H,W,C) fp32 -> xt (B,W,H,Cperm) bf16 + row sums R[b*56+h][k']
__global__ __launch_bounds__(384)
void prep_x(const float* __restrict__ x, unsigned short* __restrict__ xt,
            float* __restrict__ R)
{
    __shared__ float buf[4][CC];
    int bid = blockIdx.x;            // b*56 + h
    int b = bid / HH, h = bid - b*HH;
    int t = threadIdx.x;
    int wsub = t / 96, q = t - wsub*96;       // quad q -> channels 4q..4q+3
    int kd0 = fwdp(4*q), kd1 = fwdp(4*q+1), kd2 = fwdp(4*q+2), kd3 = fwdp(4*q+3);
    const float* xp = x + ((size_t)bid*WWD)*CC;
    unsigned short* xo = xt + ((size_t)b*HWW + h)*CC + t;
    float rs = 0.f;
    for (int w0 = 0; w0 < WWD; w0 += 4) {
        float4 v = *(const float4*)(xp + (size_t)(w0 + wsub)*CC + 4*q);
        buf[wsub][kd0] = v.x; buf[wsub][kd1] = v.y;
        buf[wsub][kd2] = v.z; buf[wsub][kd3] = v.w;
        __syncthreads();
        #pragma unroll
        for (int i = 0; i < 4; ++i) {
            float fv = buf[i][t];
            rs += fv;
            xo[(size_t)(w0 + i)*HH*CC] = f2bf(fv);
        }
        __syncthreads();
    }
    R[(size_t)bid*CC + t] = rs;
}

// means: coalesced R reads in k'-order, border-corrected, scatter to natural-c order
__global__ __launch_bounds__(384)
void mean_k(const float* __restrict__ R,
            float* __restrict__ mhp, float* __restrict__ mcp)
{
    int b = blockIdx.x, t = threadIdx.x;
    const float* Rb = R + (size_t)b*HH*CC;
    float S = 0.f;
    #pragma unroll 8
    for (int h = 0; h < HH; ++h) S += Rb[(size_t)h*CC + t];
    int d = dcls(t);
    float adj = 0.f;
    if (d == 2)       adj = Rb[0*CC + t] + Rb[1*CC + t];
    else if (d == 1)  adj = Rb[0*CC + t];
    else if (d == -1) adj = Rb[55*CC + t];
    else if (d == -2) adj = Rb[54*CC + t] + Rb[55*CC + t];
    const float inv = 1.f / (float)HWW;
    int c = invp(t);
    mhp[(size_t)b*CC + c] = (S - adj) * inv;
    mcp[(size_t)b*CC + c] = S * inv;
}

// partial dual matvec: block (p, b) sums c in [96p, 96p+96) for all t; branch-free
__global__ __launch_bounds__(384)
void avec_k(const float* __restrict__ mhp, const float* __restrict__ mcp,
            const float* __restrict__ w_h, const float* __restrict__ w_c,
            float2* __restrict__ part)
{
    __shared__ float sm[2][96];
    int p = blockIdx.x, b = blockIdx.y, t = threadIdx.x;
    if (t < 96)       sm[0][t]     = mhp[(size_t)b*CC + 96*p + t];
    else if (t < 192) sm[1][t-96]  = mcp[(size_t)b*CC + 96*p + (t-96)];
    __syncthreads();
    const float* ph = w_h + (size_t)(96*p)*CC + t;
    const float* pc = w_c + (size_t)(96*p)*CC + t;
    float sh = 0.f, sc = 0.f;
    #pragma unroll 8
    for (int e = 0; e < 96; ++e) {
        sh += sm[0][e] * ph[(size_t)e*CC];
        sc += sm[1][e] * pc[(size_t)e*CC];
    }
    part[((size_t)b*4 + p)*CC + t] = make_float2(sh, sc);
}

// combine partials -> a -> GELU MLP -> softmax -> lam + combined bias
__global__ __launch_bounds__(384)
void lam_fin(const float2* __restrict__ part,
             const float* __restrict__ b_h, const float* __restrict__ b_c,
             const float* __restrict__ w_r1, const float* __restrict__ b_r1,
             const float* __restrict__ w_r2, const float* __restrict__ b_r2,
             float2* __restrict__ lam, float* __restrict__ biasc)
{
    __shared__ float aa[CC], r1p[4][96];
    int b = blockIdx.x, t = threadIdx.x;
    float2 p0 = part[((size_t)b*4 + 0)*CC + t];
    float2 p1 = part[((size_t)b*4 + 1)*CC + t];
    float2 p2 = part[((size_t)b*4 + 2)*CC + t];
    float2 p3 = part[((size_t)b*4 + 3)*CC + t];
    float sh = p0.x + p1.x + p2.x + p3.x;
    float sc = p0.y + p1.y + p2.y + p3.y;
    aa[t] = 2.f*(sh + b_h[t]) + (sc + b_c[t]);
    __syncthreads();
    {
        int j = t % 96, p = t / 96;
        float s = 0.f;
        #pragma unroll 8
        for (int k = p*96; k < p*96 + 96; ++k) s += aa[k] * w_r1[(size_t)k*96 + j];
        r1p[p][j] = s;
    }
    __syncthreads();
    if (t < 96) {
        float s = r1p[0][t] + r1p[1][t] + r1p[2][t] + r1p[3][t] + b_r1[t];
        r1p[0][t] = 0.5f*s*(1.f + erff(s*0.70710678118654752f));
    }
    __syncthreads();
    float s0 = b_r2[3*t], s1 = b_r2[3*t+1], s2 = b_r2[3*t+2];
    #pragma unroll 8
    for (int q = 0; q < 96; ++q) {
        float rv = r1p[0][q];
        const float* wp = w_r2 + (size_t)q*(3*CC) + 3*t;
        s0 += rv*wp[0]; s1 += rv*wp[1]; s2 += rv*wp[2];
    }
    float mx = fmaxf(s0, fmaxf(s1, s2));
    float e0 = expf(s0-mx), e1 = expf(s1-mx), e2 = expf(s2-mx);
    float dn = 1.f/(e0+e1+e2);
    float lh = (e0+e1)*dn, lc = e2*dn;
    lam[(size_t)b*CC + t] = make_float2(lh, lc);
    biasc[(size_t)b*CC + t] = lh*b_h[t] + lc*b_c[t];
}

// Register-fragment-ordered B images from raw fp32 weights; parallel over b.
// Frag (kt, wnx, ni, lane): 16B = B[n][k0..k0+7], n = wnx*96+ni*16+(lane&15),
// k0 = kt*32+(lane>>4)*8. Tile = 24576 B.
__global__ __launch_bounds__(256)
void wcomb2(const float* __restrict__ w_h, const float* __restrict__ w_c,
            const float* __restrict__ w_p, const float2* __restrict__ lam,
            char* __restrict__ wB3, char* __restrict__ wP3)
{
    int idx = blockIdx.x*256 + threadIdx.x;
    const int NB = 16*24*1536;
    if (idx < NB) {
        int b = idx / (24*1536);
        int rem = idx - b*(24*1536);
        int kt = rem / 1536, f = rem - kt*1536;
        int wnx = f / 384, r = f - wnx*384;
        int ni = r / 64, lane = r - ni*64;
        int n = wnx*96 + ni*16 + (lane & 15);
        int k0 = kt*32 + ((lane >> 4) << 3);
        bool hpart = k0 < 384;
        const float* src = hpart ? w_h : w_c;
        int koff = hpart ? k0 : (k0 - 384);
        float2 L = lam[(size_t)b*CC + n];
        float s = hpart ? L.x : L.y;
        bf16x8 o;
        #pragma unroll
        for (int e = 0; e < 8; ++e)
            o[e] = (short)f2bf(s * src[(size_t)invp(koff + e)*CC + n]);
        *(bf16x8*)(wB3 + (size_t)b*WB_BSTRIDE + (size_t)kt*24576 + wnx*6144 + ni*1024 + lane*16) = o;
    } else {
        int j = idx - NB;
        int kt = j / 1536, f = j - kt*1536;
        int wnx = f / 384, r = f - wnx*384;
        int ni = r / 64, lane = r - ni*64;
        int n = wnx*96 + ni*16 + (lane & 15);
        int k0 = kt*32 + ((lane >> 4) << 3);
        bf16x8 o;
        #pragma unroll
        for (int e = 0; e < 8; ++e) o[e] = (short)f2bf(w_p[(size_t)(k0 + e)*CC + n]);
        *(bf16x8*)(wP3 + (size_t)kt*24576 + wnx*6144 + ni*1024 + lane*16) = o;
    }
}

// Fused, barrier-free K-loop: A panel in LDS (read-only), B streamed to registers
// in MFMA fragment order with depth-2 rotating prefetch. Only 3 barriers total.
__global__ __launch_bounds__(512, 2)
void g12r(const unsigned short* __restrict__ xt,
          const char* __restrict__ wB3,
          const char* __restrict__ wP3,
          const float* __restrict__ biasc,
          const float* __restrict__ b_p,
          float* __restrict__ out)
{
    __shared__ char Asm[132*768];   // 101,376 B: A panel (halo rows m0-2..m0+129); later A'

    const int tid = threadIdx.x;
    int bid = blockIdx.x;
    bid = (bid & 7)*(NBLK3/8) + (bid >> 3);       // XCD-chunked swizzle (400=8*50)
    const int b  = bid / MBPB;
    const int m0 = (bid - b*MBPB) * 128;          // batch-local row base
    const size_t gbase = (size_t)b * HWW;

    const int lane = tid & 63;
    const int wid  = tid >> 6;
    const int l16  = lane & 15;
    const int lhi  = lane >> 4;
    const int wm  = (wid >> 2) * 64;              // 2 M-waves
    const int wnx = wid & 3;                      // 4 N-waves
    const int wn  = wnx * 96;

    const char* bptr1 = wB3 + (size_t)b*WB_BSTRIDE + wnx*6144 + lane*16;
    const char* bptr2 = wP3 + wnx*6144 + lane*16;

    // prologue B loads: tiles 0,1 into sets 0,1 (first in VMEM queue)
    int4v bb[3][6];
    #pragma unroll
    for (int ni = 0; ni < 6; ++ni)
        bb[0][ni] = *(const int4v*)(bptr1 + ni*1024);
    #pragma unroll
    for (int ni = 0; ni < 6; ++ni)
        bb[1][ni] = *(const int4v*)(bptr1 + 24576 + ni*1024);

    // stage A panel (reg-staged, oct-XOR swizzle), nontemporal reads
    #pragma unroll
    for (int it = 0; it < 13; ++it) {
        int s = it*512 + tid;
        if (s < 132*48) {
            int row = s / 48, oct = s - row*48;
            int g = m0 - 2 + row;
            g = g < 0 ? 0 : (g >= HWW ? HWW-1 : g);
            int4v v = __builtin_nontemporal_load(
                (const int4v*)(xt + (gbase + g)*CC + oct*8));
            *(int4v*)(Asm + row*768 + ((oct ^ (row & 7)) << 4)) = v;
        }
    }

    int rbase[4], hmod[4];
    #pragma unroll
    for (int mi = 0; mi < 4; ++mi) {
        rbase[mi] = wm + mi*16 + l16 + 2;
        hmod[mi]  = (m0 + wm + mi*16 + l16) % HH;
    }

    f32x4 acc[4][6];
    #pragma unroll
    for (int mi = 0; mi < 4; ++mi)
        #pragma unroll
        for (int ni = 0; ni < 6; ++ni) acc[mi][ni] = (f32x4)0.f;

    __syncthreads();   // A panel ready (also drains prologue B, one-time)

    // ---- phase 1: 24 BK=32 steps, no barriers, rotating depth-2 B prefetch ----
    #pragma unroll
    for (int kt = 0; kt < 24; ++kt) {
        const char* nx = (kt + 2 < 24) ? (bptr1 + (size_t)(kt+2)*24576)
                                       : (bptr2 + (size_t)(kt+2-24)*24576);
        #pragma unroll
        for (int ni = 0; ni < 6; ++ni)
            bb[(kt+2)%3][ni] = *(const int4v*)(nx + ni*1024);

        int4v a[4];
        if (kt < 12) {
            const int octg = kt*4 + lhi;
            const int d = octg < 6 ? 2 : octg < 18 ? 1 : octg < 30 ? 0 : octg < 42 ? -1 : -2;
            #pragma unroll
            for (int mi = 0; mi < 4; ++mi) {
                int r = rbase[mi] + d;
                int4v v = *(const int4v*)(Asm + r*768 + ((octg ^ (r & 7)) << 4));
                int ok = ((unsigned)(hmod[mi] + d) < (unsigned)HH) ? ~0 : 0;
                a[mi] = v & ok;
            }
        } else {
            const int octg = (kt-12)*4 + lhi;
            #pragma unroll
            for (int mi = 0; mi < 4; ++mi) {
                int r = rbase[mi];
                a[mi] = *(const int4v*)(Asm + r*768 + ((octg ^ (r & 7)) << 4));
            }
        }
        __builtin_amdgcn_s_setprio(1);
        #pragma unroll
        for (int mi = 0; mi < 4; ++mi)
            #pragma unroll
            for (int ni = 0; ni < 6; ++ni)
                acc[mi][ni] = __builtin_amdgcn_mfma_f32_16x16x32_bf16(
                    asbf(a[mi]), asbf(bb[kt%3][ni]), acc[mi][ni], 0, 0, 0);
        __builtin_amdgcn_s_setprio(0);
    }

    __syncthreads();   // all waves done reading A panel

    // ---- A' -> LDS (rows 0..127), bf16, + biasc ----
    #pragma unroll
    for (int ni = 0; ni < 6; ++ni) {
        int n = wn + ni*16 + l16;
        float bc = biasc[(size_t)b*CC + n];
        int oct = n >> 3, nb = (n & 7)*2;
        #pragma unroll
        for (int mi = 0; mi < 4; ++mi) {
            int row0 = wm + mi*16 + lhi*4;
            #pragma unroll
            for (int j = 0; j < 4; ++j) {
                int row = row0 + j;
                *(unsigned short*)(Asm + row*768 + ((oct ^ (row & 7)) << 4) + nb)
                    = f2bf(acc[mi][ni][j] + bc);
            }
        }
    }
    __syncthreads();   // A' visible to all

    #pragma unroll
    for (int mi = 0; mi < 4; ++mi)
        #pragma unroll
        for (int ni = 0; ni < 6; ++ni) acc[mi][ni] = (f32x4)0.f;

    // ---- phase 2: 12 steps, barrier-free; pipeline continues across handoff ----
    #pragma unroll
    for (int g2 = 0; g2 < 12; ++g2) {
        if (g2 + 2 < 12) {
            #pragma unroll
            for (int ni = 0; ni < 6; ++ni)
                bb[(g2+2)%3][ni] = *(const int4v*)(bptr2 + (size_t)(g2+2)*24576 + ni*1024);
        }
        const int octg = g2*4 + lhi;
        int4v a[4];
        #pragma unroll
        for (int mi = 0; mi < 4; ++mi) {
            int r = wm + mi*16 + l16;
            a[mi] = *(const int4v*)(Asm + r*768 + ((octg ^ (r & 7)) << 4));
        }
        __builtin_amdgcn_s_setprio(1);
        #pragma unroll
        for (int mi = 0; mi < 4; ++mi)
            #pragma unroll
            for (int ni = 0; ni < 6; ++ni)
                acc[mi][ni] = __builtin_amdgcn_mfma_f32_16x16x32_bf16(
                    asbf(a[mi]), asbf(bb[g2%3][ni]), acc[mi][ni], 0, 0, 0);
        __builtin_amdgcn_s_setprio(0);
    }

    // ---- epilogue: un-permute rows (W-major -> H-major), fp32 nontemporal ----
    #pragma unroll
    for (int ni = 0; ni < 6; ++ni) {
        int n = wn + ni*16 + l16;
        float bpv = b_p[n];
        #pragma unroll
        for (int mi = 0; mi < 4; ++mi) {
            #pragma unroll
            for (int j = 0; j < 4; ++j) {
                int rl = m0 + wm + mi*16 + lhi*4 + j;
                if (rl < HWW) {
                    int hh = rl % HH, ww = rl / HH;
                    __builtin_nontemporal_store(acc[mi][ni][j] + bpv,
                        out + (gbase + (size_t)(hh*WWD + ww))*CC + n);
                }
            }
        }
    }
}

extern "C" void kernel_launch(void* const* d_in, const int* in_sizes, int n_in,
                              void* d_out, int out_size, void* d_ws, size_t ws_size,
                              hipStream_t stream)
{
    const float* x    = (const float*)d_in[0];
    const float* w_h  = (const float*)d_in[1];
    const float* b_h  = (const float*)d_in[2];
    const float* w_c  = (const float*)d_in[3];
    const float* b_c  = (const float*)d_in[4];
    const float* w_r1 = (const float*)d_in[5];
    const float* b_r1 = (const float*)d_in[6];
    const float* w_r2 = (const float*)d_in[7];
    const float* b_r2 = (const float*)d_in[8];
    const float* w_p  = (const float*)d_in[9];
    const float* b_p  = (const float*)d_in[10];
    float* out = (float*)d_out;

    char* ws = (char*)d_ws;
    unsigned short* xt  = (unsigned short*)(ws);                 // 38,535,168
    char* wB3           = ws + 38535168;                         //  9,437,184
    char* wP3           = ws + 47972352;                         //    294,912
    float* R            = (float*)(ws + 48267264);               //  1,376,256
    float2* lam         = (float2*)(ws + 49643520);              //     49,152
    float* biasc        = (float*)(ws + 49692672);               //     24,576
    float* mhp          = (float*)(ws + 49717248);               //     24,576
    float* mcp          = (float*)(ws + 49741824);               //     24,576
    float2* part        = (float2*)(ws + 49766400);              //    196,608

    prep_x<<<16*HH, 384, 0, stream>>>(x, xt, R);
    mean_k<<<16, 384, 0, stream>>>(R, mhp, mcp);
    avec_k<<<dim3(4, 16), 384, 0, stream>>>(mhp, mcp, w_h, w_c, part);
    lam_fin<<<16, 384, 0, stream>>>(part, b_h, b_c, w_r1, b_r1, w_r2, b_r2, lam, biasc);
    wcomb2<<<(16*24*1536 + 12*1536)/256, 256, 0, stream>>>(w_h, w_c, w_p, lam, wB3, wP3);
    g12r<<<NBLK3, 512, 0, stream>>>(xt, wB3, wP3, biasc, b_p, out);
}